// Round 8
// baseline (1843.528 us; speedup 1.0000x reference)
//
#include <hip/hip_runtime.h>
#include <math.h>

// Problem constants
#define RR 16384        // B*N rows
#define DD 512          // feature dim
#define CC 4096         // codebook size
#define QQ 4            // num quantizers
#define NG 64           // 64-col groups (CC/64) -- top-2-per-group keys
#define QOUT_SZ (RR*DD)
#define IDX_OFF QOUT_SZ
#define LOSS_OFF (QOUT_SZ + RR*QQ)
#define LOSS_COEF (1.25f / 8388608.0f)
#define NBLK_FIN (RR/4)  // finalize blocks per dispatch (4096)

// Workspace layout (float offsets)
#define WS_RESID 0
#define WS_CBN   (RR*DD)                    // 8388608
#define WS_RNRM  (WS_CBN + CC*DD)           // 10485760
#define WS_PV    (WS_RNRM + RR)             // 10502144  (pk: RR*128 u32 keys = 8 MB)
#define WS_PI    (WS_PV + RR*32*4)          // loss partials [QQ][NBLK_FIN]
#define WS_F16   (WS_PI + RR*32*4 + 4)      // 16B aligned
// f16 region (offsets in halves from WS_F16 base)
#define F16_A 0
#define F16_B (RR*DD)

typedef _Float16 f16x8 __attribute__((ext_vector_type(8)));
typedef float f32x4 __attribute__((ext_vector_type(4)));

__device__ __forceinline__ float waveSum(float v) {
#pragma unroll
    for (int m = 1; m < 64; m <<= 1) v += __shfl_xor(v, m, 64);
    return v;
}

// interleaved N-way wave sum: N independent butterfly chains for ILP
template <int N>
__device__ __forceinline__ void waveSumN(float* v) {
#pragma unroll
    for (int m = 1; m < 64; m <<= 1) {
#pragma unroll
        for (int j = 0; j < N; ++j) v[j] += __shfl_xor(v[j], m, 64);
    }
}

// ---------- packed-key top-k machinery ----------
// key = monotone(f32 sim) truncated to top-20 bits | (4095 - col).
__device__ __forceinline__ unsigned packKey(float v, int c) {
    unsigned u = __float_as_uint(v);
    u ^= (unsigned)((int)u >> 31) | 0x80000000u;   // monotone total order
    return (u & 0xFFFFF000u) | (unsigned)(4095 - c);
}

__device__ __forceinline__ void ceDesc(unsigned &a, unsigned &b) {
    unsigned mn = a > b ? b : a;
    a = a > b ? a : b;
    b = mn;
}

// merge partner's sorted-desc 4-list into mine (bitonic top-half + sort).
__device__ __forceinline__ void merge4(unsigned k[4],
                                       unsigned b0, unsigned b1,
                                       unsigned b2, unsigned b3) {
    k[0] = k[0] > b3 ? k[0] : b3;
    k[1] = k[1] > b2 ? k[1] : b2;
    k[2] = k[2] > b1 ? k[2] : b1;
    k[3] = k[3] > b0 ? k[3] : b0;
    ceDesc(k[0], k[2]); ceDesc(k[1], k[3]);
    ceDesc(k[0], k[1]); ceDesc(k[2], k[3]);
}

__device__ __forceinline__ void merge4Shfl(unsigned k[4], int m) {
    unsigned b0 = __shfl_xor(k[0], m, 64);
    unsigned b1 = __shfl_xor(k[1], m, 64);
    unsigned b2 = __shfl_xor(k[2], m, 64);
    unsigned b3 = __shfl_xor(k[3], m, 64);
    merge4(k, b0, b1, b2, b3);
}

// ---------------- init: resid = x, qout = 0 ----------------
__global__ void initK(const float* __restrict__ x, float* __restrict__ resid,
                      float* __restrict__ dout) {
    int i = blockIdx.x * blockDim.x + threadIdx.x;
    int stride = gridDim.x * blockDim.x;
    for (; i < QOUT_SZ; i += stride) { resid[i] = x[i]; dout[i] = 0.0f; }
}

// ---------------- implicit_cb = codebooks[q] @ weights[q]^T ----------------
__global__ __launch_bounds__(256) void gemmCbK(const float* __restrict__ A,
                                               const float* __restrict__ W,
                                               float* __restrict__ out) {
    __shared__ float As[32][64];
    __shared__ float Bs[32][64];
    int t = threadIdx.x;
    int tx = t & 15, ty = t >> 4;
    int cBase = blockIdx.x * 64;
    int dBase = blockIdx.y * 64;
    int f = t & 7;
    int mq = t >> 3;
    float acc[4][4] = {};
    for (int k0 = 0; k0 < DD; k0 += 32) {
        __syncthreads();
#pragma unroll
        for (int p = 0; p < 2; ++p) {
            int m = mq + p * 32;
            float4 av = *(const float4*)&A[(size_t)(cBase + m) * DD + k0 + f * 4];
            As[f*4+0][m] = av.x; As[f*4+1][m] = av.y; As[f*4+2][m] = av.z; As[f*4+3][m] = av.w;
            float4 wv = *(const float4*)&W[(size_t)(dBase + m) * DD + k0 + f * 4];
            Bs[f*4+0][m] = wv.x; Bs[f*4+1][m] = wv.y; Bs[f*4+2][m] = wv.z; Bs[f*4+3][m] = wv.w;
        }
        __syncthreads();
#pragma unroll
        for (int kk = 0; kk < 32; ++kk) {
            float4 a4 = *(const float4*)&As[kk][ty * 4];
            float4 b4 = *(const float4*)&Bs[kk][tx * 4];
            float a[4] = {a4.x, a4.y, a4.z, a4.w};
            float b[4] = {b4.x, b4.y, b4.z, b4.w};
#pragma unroll
            for (int i = 0; i < 4; ++i)
#pragma unroll
                for (int j = 0; j < 4; ++j) acc[i][j] += a[i] * b[j];
        }
    }
#pragma unroll
    for (int i = 0; i < 4; ++i) {
        float4 v = make_float4(acc[i][0], acc[i][1], acc[i][2], acc[i][3]);
        *(float4*)&out[(size_t)(cBase + ty * 4 + i) * DD + dBase + tx * 4] = v;
    }
}

// ------- normalize cbn rows in place + emit f16 copy (one wave/row) ----------
__global__ void rowNormCvtK(float* __restrict__ buf, _Float16* __restrict__ bf16) {
    int wave = threadIdx.x >> 6, lane = threadIdx.x & 63;
    int row = blockIdx.x * 4 + wave;
    float* p = buf + (size_t)row * DD;
    float4 v0 = *(float4*)&p[lane * 8];
    float4 v1 = *(float4*)&p[lane * 8 + 4];
    float ss = v0.x*v0.x + v0.y*v0.y + v0.z*v0.z + v0.w*v0.w
             + v1.x*v1.x + v1.y*v1.y + v1.z*v1.z + v1.w*v1.w;
    ss = waveSum(ss);
    float nrm = fmaxf(sqrtf(ss), 1e-12f);
    float vals[8] = {v0.x/nrm, v0.y/nrm, v0.z/nrm, v0.w/nrm,
                     v1.x/nrm, v1.y/nrm, v1.z/nrm, v1.w/nrm};
    *(float4*)&p[lane * 8]     = make_float4(vals[0], vals[1], vals[2], vals[3]);
    *(float4*)&p[lane * 8 + 4] = make_float4(vals[4], vals[5], vals[6], vals[7]);
    f16x8 hv;
#pragma unroll
    for (int j = 0; j < 8; ++j) hv[j] = (_Float16)vals[j];
    *(f16x8*)&bf16[(size_t)row * DD + lane * 8] = hv;
}

// ------- resid row norms + f16 copy of RAW resid (q=0 only) ------------------
__global__ void residCvtK(const float* __restrict__ resid,
                          float* __restrict__ rnrm, _Float16* __restrict__ af16) {
    int wave = threadIdx.x >> 6, lane = threadIdx.x & 63;
    int row = blockIdx.x * 4 + wave;
    const float* p = resid + (size_t)row * DD;
    float4 v0 = *(const float4*)&p[lane * 8];
    float4 v1 = *(const float4*)&p[lane * 8 + 4];
    float vals[8] = {v0.x, v0.y, v0.z, v0.w, v1.x, v1.y, v1.z, v1.w};
    float ss = 0.f;
#pragma unroll
    for (int j = 0; j < 8; ++j) ss += vals[j] * vals[j];
    ss = waveSum(ss);
    if (lane == 0) rnrm[row] = fmaxf(sqrtf(ss), 1e-12f);
    f16x8 hv;
#pragma unroll
    for (int j = 0; j < 8; ++j) hv[j] = (_Float16)vals[j];
    *(f16x8*)&af16[(size_t)row * DD + lane * 8] = hv;
}

// ---------------- single-pass f16 MFMA sim GEMM + fused top-2 ----------------
// R7: ZERO-LDS, ZERO-BARRIER direct-to-register structure.
// Post-mortems R3/R6: every re-tile of the 2-barrier LDS K-loop regressed or
// tied; R4's 112 us has MfmaUtil 27% with MFMA needing only ~30 us -- the
// barrier-coupled stage->vmcnt(0)->compute chain is structural. Fix: the MFMA
// fragment per lane is 16 CONTIGUOUS bytes of a row (lane(quad,l15) holds
// row l15, k = s*32 + quad*8..+7 -- exactly what the verified LDS path
// delivered after its XOR swizzle). Load it straight from global: per
// instruction 16 rows x 64 contiguous B (64-B sectors), A/B are L2/L3
// resident (16 MB each). Each wave free-runs a register-only 2-deep pipeline:
// 6x 16-B loads (all folded to offset:N off 6 base pointers) + 8 MFMAs per
// 32-k step. No __syncthreads anywhere; TLP covers L2 latency (256-thread
// blocks -> 1-wave residency granularity). Cost: 2x A / 4x B read redundancy
// paid from L2. Wave tile stays R4's proven 32x64 acc[2][4]; epilogue
// byte-identical (gkey = blockIdx.y, 64-col blocks).
__global__ __launch_bounds__(256)
void simMfmaK(
    const _Float16* __restrict__ Af16, const _Float16* __restrict__ Bf16,
    unsigned* __restrict__ pk) {
    int t = threadIdx.x, w = t >> 6, lane = t & 63;
    int rowBase = blockIdx.x * 128;
    int cBase = blockIdx.y * 64;
    int mbase = w * 32;
    int l15 = lane & 15, quad = lane >> 4;

    f32x4 acc[2][4];
#pragma unroll
    for (int i = 0; i < 2; ++i)
#pragma unroll
        for (int j = 0; j < 4; ++j) acc[i][j] = (f32x4){0.f, 0.f, 0.f, 0.f};

    // base pointers: lane(quad,l15) reads row base+l15, k-chunk quad
    const _Float16* A0 = Af16 + (size_t)(rowBase + mbase + l15) * DD + quad * 8;
    const _Float16* A1 = A0 + 16 * DD;
    const _Float16* B0 = Bf16 + (size_t)(cBase + l15) * DD + quad * 8;
    const _Float16* B1 = B0 + 16 * DD;
    const _Float16* B2 = B0 + 32 * DD;
    const _Float16* B3 = B0 + 48 * DD;

#define LDSTEP(s) ((s) * 32)   // 32 f16 per k-step along a row
    f16x8 aA0, aA1, bA0, bA1, bA2, bA3;
    f16x8 aB0, aB1, bB0, bB1, bB2, bB3;

    aA0 = *(const f16x8*)&A0[LDSTEP(0)]; aA1 = *(const f16x8*)&A1[LDSTEP(0)];
    bA0 = *(const f16x8*)&B0[LDSTEP(0)]; bA1 = *(const f16x8*)&B1[LDSTEP(0)];
    bA2 = *(const f16x8*)&B2[LDSTEP(0)]; bA3 = *(const f16x8*)&B3[LDSTEP(0)];

#pragma unroll
    for (int s = 0; s < 16; s += 2) {
        // prefetch step s+1 into B-set (s+1 <= 15 always)
        aB0 = *(const f16x8*)&A0[LDSTEP(s + 1)]; aB1 = *(const f16x8*)&A1[LDSTEP(s + 1)];
        bB0 = *(const f16x8*)&B0[LDSTEP(s + 1)]; bB1 = *(const f16x8*)&B1[LDSTEP(s + 1)];
        bB2 = *(const f16x8*)&B2[LDSTEP(s + 1)]; bB3 = *(const f16x8*)&B3[LDSTEP(s + 1)];
        // compute step s from A-set
        acc[0][0] = __builtin_amdgcn_mfma_f32_16x16x32_f16(aA0, bA0, acc[0][0], 0, 0, 0);
        acc[1][0] = __builtin_amdgcn_mfma_f32_16x16x32_f16(aA1, bA0, acc[1][0], 0, 0, 0);
        acc[0][1] = __builtin_amdgcn_mfma_f32_16x16x32_f16(aA0, bA1, acc[0][1], 0, 0, 0);
        acc[1][1] = __builtin_amdgcn_mfma_f32_16x16x32_f16(aA1, bA1, acc[1][1], 0, 0, 0);
        acc[0][2] = __builtin_amdgcn_mfma_f32_16x16x32_f16(aA0, bA2, acc[0][2], 0, 0, 0);
        acc[1][2] = __builtin_amdgcn_mfma_f32_16x16x32_f16(aA1, bA2, acc[1][2], 0, 0, 0);
        acc[0][3] = __builtin_amdgcn_mfma_f32_16x16x32_f16(aA0, bA3, acc[0][3], 0, 0, 0);
        acc[1][3] = __builtin_amdgcn_mfma_f32_16x16x32_f16(aA1, bA3, acc[1][3], 0, 0, 0);
        // prefetch step s+2 into A-set (skip past end)
        if (s + 2 < 16) {
            aA0 = *(const f16x8*)&A0[LDSTEP(s + 2)]; aA1 = *(const f16x8*)&A1[LDSTEP(s + 2)];
            bA0 = *(const f16x8*)&B0[LDSTEP(s + 2)]; bA1 = *(const f16x8*)&B1[LDSTEP(s + 2)];
            bA2 = *(const f16x8*)&B2[LDSTEP(s + 2)]; bA3 = *(const f16x8*)&B3[LDSTEP(s + 2)];
        }
        // compute step s+1 from B-set
        acc[0][0] = __builtin_amdgcn_mfma_f32_16x16x32_f16(aB0, bB0, acc[0][0], 0, 0, 0);
        acc[1][0] = __builtin_amdgcn_mfma_f32_16x16x32_f16(aB1, bB0, acc[1][0], 0, 0, 0);
        acc[0][1] = __builtin_amdgcn_mfma_f32_16x16x32_f16(aB0, bB1, acc[0][1], 0, 0, 0);
        acc[1][1] = __builtin_amdgcn_mfma_f32_16x16x32_f16(aB1, bB1, acc[1][1], 0, 0, 0);
        acc[0][2] = __builtin_amdgcn_mfma_f32_16x16x32_f16(aB0, bB2, acc[0][2], 0, 0, 0);
        acc[1][2] = __builtin_amdgcn_mfma_f32_16x16x32_f16(aB1, bB2, acc[1][2], 0, 0, 0);
        acc[0][3] = __builtin_amdgcn_mfma_f32_16x16x32_f16(aB0, bB3, acc[0][3], 0, 0, 0);
        acc[1][3] = __builtin_amdgcn_mfma_f32_16x16x32_f16(aB1, bB3, acc[1][3], 0, 0, 0);
    }

    // epilogue: per wave, top-2 per row over its 64 columns, packed keys.
    // D layout: lane,reg r -> row = quad*4+r (in 16-tile), col = l15
    int gkey = blockIdx.y;                // global 64-col group index (0..63)
#pragma unroll
    for (int tm = 0; tm < 2; ++tm) {
#pragma unroll
        for (int r = 0; r < 4; ++r) {
            unsigned t0 = packKey(acc[tm][0][r], cBase + 0 * 16 + l15);
            unsigned t1 = packKey(acc[tm][1][r], cBase + 1 * 16 + l15);
            unsigned t2 = packKey(acc[tm][2][r], cBase + 2 * 16 + l15);
            unsigned t3 = packKey(acc[tm][3][r], cBase + 3 * 16 + l15);
            // per-lane sorted top-2 of 4 keys
            ceDesc(t0, t1); ceDesc(t2, t3);
            unsigned k0 = t0 > t2 ? t0 : t2;
            unsigned mn = t0 > t2 ? t2 : t0;
            unsigned mx = t1 > t3 ? t1 : t3;
            unsigned k1 = mn > mx ? mn : mx;
            // 16-lane butterfly merge of sorted pairs
#pragma unroll
            for (int m = 1; m < 16; m <<= 1) {
                unsigned b0 = __shfl_xor(k0, m, 64);
                unsigned b1 = __shfl_xor(k1, m, 64);
                unsigned m0 = k0 > b0 ? k0 : b0;
                unsigned n0 = k0 > b0 ? b0 : k0;
                unsigned m1 = k1 > b1 ? k1 : b1;
                k0 = m0;
                k1 = n0 > m1 ? n0 : m1;
            }
            if (l15 == 0) {
                int rowg = rowBase + mbase + tm * 16 + quad * 4 + r;
                *(uint2*)&pk[(size_t)rowg * 128 + gkey * 2] = make_uint2(k0, k1);
            }
        }
    }
}

// -------- finalize: merge group top-2s, fp32 rescore, rotation, updates,
//          and emit next-q residual f16 + rnrm (fused residCvt) --------------
__global__ void finalizeK(float* __restrict__ resid,
                          float* __restrict__ rnrm,
                          const float* __restrict__ cbn,
                          const unsigned* __restrict__ pk,
                          float* __restrict__ dout,
                          float* __restrict__ lossPart,
                          _Float16* __restrict__ af16, int q) {
    __shared__ float sL[4];
    int wave = threadIdx.x >> 6, lane = threadIdx.x & 63;
    int row = blockIdx.x * 4 + wave;
    float* xr = resid + (size_t)row * DD;
    float nrm = rnrm[row];
    float4 a0 = *(float4*)&xr[lane * 8];
    float4 a1 = *(float4*)&xr[lane * 8 + 4];
    float orig[8] = {a0.x,a0.y,a0.z,a0.w,a1.x,a1.y,a1.z,a1.w};
    float x[8];
#pragma unroll
    for (int j = 0; j < 8; ++j) x[j] = orig[j] / nrm;   // x_n per reference

    // 128 keys per row (64 groups x sorted top-2); lane l holds group l's pair
    uint2 kp = *(const uint2*)&pk[(size_t)row * 128 + lane * 2];
    unsigned k[4] = {kp.x, kp.y, 0u, 0u};   // sorted desc (zeros lose to real keys)
#pragma unroll
    for (int m = 1; m < 64; m <<= 1) merge4Shfl(k, m);
    int cand[4];
#pragma unroll
    for (int j = 0; j < 4; ++j)
        cand[j] = 4095 - (int)(__shfl(k[j], 0, 64) & 0xFFFu);

    // exact fp32 rescore of the 4 nominated candidates on the normalized row.
    float cv[4][8];
#pragma unroll
    for (int j = 0; j < 4; ++j) {
        const float* cbj = cbn + (size_t)cand[j] * DD;
        float4 c0 = *(const float4*)&cbj[lane * 8];
        float4 c1 = *(const float4*)&cbj[lane * 8 + 4];
        cv[j][0]=c0.x; cv[j][1]=c0.y; cv[j][2]=c0.z; cv[j][3]=c0.w;
        cv[j][4]=c1.x; cv[j][5]=c1.y; cv[j][6]=c1.z; cv[j][7]=c1.w;
    }
    float s[4];
#pragma unroll
    for (int j = 0; j < 4; ++j) {
        float acc = 0.f;
#pragma unroll
        for (int e = 0; e < 8; ++e) acc += x[e] * cv[j][e];
        s[j] = acc;
    }
    waveSumN<4>(s);
    float sBest = -3e38f; int idx = 0x7fffffff, sel = 0;
#pragma unroll
    for (int j = 0; j < 4; ++j) {
        if (s[j] > sBest || (s[j] == sBest && cand[j] < idx)) {
            sBest = s[j]; idx = cand[j]; sel = j;
        }
    }

    // winning row from registers (wave-uniform sel -> cndmask tree)
    float qv[8];
#pragma unroll
    for (int e = 0; e < 8; ++e)
        qv[e] = sel == 0 ? cv[0][e] : sel == 1 ? cv[1][e]
              : sel == 2 ? cv[2][e] : cv[3][e];

    float red3[3] = {0.f, 0.f, 0.f};   // ns2, nt2, lrow
#pragma unroll
    for (int j = 0; j < 8; ++j) {
        red3[0] += x[j] * x[j];
        red3[1] += qv[j] * qv[j];
        float d = x[j] - qv[j];
        red3[2] += d * d;
    }
    waveSumN<3>(red3);
    float ns = sqrtf(red3[0]), nt = sqrtf(red3[1]), lrow = red3[2];

    float u[8], qn[8], wv[8];
    float nw2 = 0.f;
#pragma unroll
    for (int j = 0; j < 8; ++j) {
        u[j] = x[j] / ns;
        qn[j] = qv[j] / nt;
        wv[j] = u[j] + qn[j];
        nw2 += wv[j] * wv[j];
    }
    nw2 = waveSum(nw2);
    float nw = fmaxf(sqrtf(nw2), 1e-12f);
    float red2[2] = {0.f, 0.f};        // dew, deu
#pragma unroll
    for (int j = 0; j < 8; ++j) {
        wv[j] = wv[j] / nw;
        red2[0] += x[j] * wv[j];
        red2[1] += x[j] * u[j];
    }
    waveSumN<2>(red2);
    float dew = red2[0], deu = red2[1];
    float scale = nt / ns;

    float r[8], nres[8];
    float ss = 0.f;
#pragma unroll
    for (int j = 0; j < 8; ++j) {
        r[j] = (x[j] - 2.0f * dew * wv[j] + 2.0f * deu * qn[j]) * scale;
        nres[j] = orig[j] - r[j];
        ss += nres[j] * nres[j];
    }

    // residual -= r ; emit f16 residual + next rnrm (fused residCvt)
    *(float4*)&xr[lane * 8]     = make_float4(nres[0], nres[1], nres[2], nres[3]);
    *(float4*)&xr[lane * 8 + 4] = make_float4(nres[4], nres[5], nres[6], nres[7]);
    ss = waveSum(ss);
    if (lane == 0) rnrm[row] = fmaxf(sqrtf(ss), 1e-12f);
    f16x8 hv;
#pragma unroll
    for (int j = 0; j < 8; ++j) hv[j] = (_Float16)nres[j];
    *(f16x8*)&af16[(size_t)row * DD + lane * 8] = hv;

    float* op = dout + (size_t)row * DD;
    float4 o0 = *(float4*)&op[lane * 8];
    float4 o1 = *(float4*)&op[lane * 8 + 4];
    o0.x += r[0]; o0.y += r[1]; o0.z += r[2]; o0.w += r[3];
    o1.x += r[4]; o1.y += r[5]; o1.z += r[6]; o1.w += r[7];
    *(float4*)&op[lane * 8] = o0;
    *(float4*)&op[lane * 8 + 4] = o1;

    if (lane == 0) {
        dout[IDX_OFF + row * 4 + q] = (float)idx;
        sL[wave] = lrow;
    }
    __syncthreads();
    if (threadIdx.x == 0) {
        lossPart[(size_t)q * NBLK_FIN + blockIdx.x] =
            (sL[0] + sL[1] + sL[2] + sL[3]) * LOSS_COEF;
    }
}

// -------- final loss reduce: one wave per q sums its 4096 block partials -----
__global__ void lossWriteK(const float* __restrict__ lossPart,
                           float* __restrict__ dout) {
    int q = threadIdx.x >> 6, lane = threadIdx.x & 63;
    float s = 0.f;
    for (int i = lane; i < NBLK_FIN; i += 64)
        s += lossPart[(size_t)q * NBLK_FIN + i];
    s = waveSum(s);
    if (lane == 0) dout[LOSS_OFF + q] = s;
}

extern "C" void kernel_launch(void* const* d_in, const int* in_sizes, int n_in,
                              void* d_out, int out_size, void* d_ws, size_t ws_size,
                              hipStream_t stream) {
    const float* x = (const float*)d_in[0];
    const float* codebooks = (const float*)d_in[1];
    const float* weights = (const float*)d_in[2];
    float* dout = (float*)d_out;
    float* w = (float*)d_ws;

    float* resid = w + WS_RESID;
    float* cbn   = w + WS_CBN;
    float* rnrm  = w + WS_RNRM;
    unsigned* pk = (unsigned*)(w + WS_PV);
    float* lossPart = w + WS_PI;
    _Float16* f16base = (_Float16*)(w + WS_F16);
    _Float16* Af16 = f16base + F16_A;
    _Float16* Bf16 = f16base + F16_B;

    initK<<<4096, 256, 0, stream>>>(x, resid, dout);
    residCvtK<<<RR / 4, 256, 0, stream>>>(resid, rnrm, Af16);

    for (int q = 0; q < QQ; ++q) {
        gemmCbK<<<dim3(CC / 64, DD / 64), 256, 0, stream>>>(
            codebooks + (size_t)q * CC * DD, weights + (size_t)q * DD * DD, cbn);
        rowNormCvtK<<<CC / 4, 256, 0, stream>>>(cbn, Bf16);
        simMfmaK<<<dim3(RR / 128, CC / 64), 256, 0, stream>>>(Af16, Bf16, pk);
        finalizeK<<<RR / 4, 256, 0, stream>>>(resid, rnrm, cbn, pk,
                                              dout, lossPart, Af16, q);
    }
    lossWriteK<<<1, 256, 0, stream>>>(lossPart, dout);
}

// Round 11
// 778.355 us; speedup vs baseline: 2.3685x; 2.3685x over previous
//
#include <hip/hip_runtime.h>
#include <math.h>

// Problem constants
#define RR 16384        // B*N rows
#define DD 512          // feature dim
#define CC 4096         // codebook size
#define QQ 4            // num quantizers
#define QOUT_SZ (RR*DD)
#define IDX_OFF QOUT_SZ
#define LOSS_OFF (QOUT_SZ + RR*QQ)
#define LOSS_COEF (1.25f / 8388608.0f)
#define NBLK_FIN (RR/4)  // finalize blocks per dispatch (4096)

// Workspace layout (float offsets) -- IDENTICAL footprint to rounds 0-7
// (79.8 MB high-water mark, proven in-bounds). R10: the R8/R9 container
// failures are suspected OOB -- R8 grew the f16 region by 9 MB. Fix: bf16
// split buffers alias DEAD regions instead of appending:
//   cbHi/cbLo (8.39 MB) -> pk region (exactly 8.39 MB; pk is written by
//     simMfmaK AFTER gemmCbMfmaK consumed the splits, read by finalizeK
//     BEFORE next q's cvtSplit -- single-stream ordering, no overlap alive)
//   wHi/wLo (1 MB) -> PI region slack (lossPart uses first 64 KB of 8.39 MB;
//     wHi starts at +128 KB)
#define WS_RESID 0
#define WS_CBN   (RR*DD)                    // 8388608
#define WS_RNRM  (WS_CBN + CC*DD)           // 10485760
#define WS_PV    (WS_RNRM + RR)             // 10502144  (pk / cbHi+cbLo)
#define WS_PI    (WS_PV + RR*32*4)          // lossPart + wHi/wLo slack
#define WS_F16   (WS_PI + RR*32*4 + 4)      // 16B aligned
// f16 region (offsets in halves from WS_F16 base) -- original extent
#define F16_A 0
#define F16_B (RR*DD)

typedef _Float16 f16x8 __attribute__((ext_vector_type(8)));
typedef short bf16x8 __attribute__((ext_vector_type(8)));
typedef float f32x4 __attribute__((ext_vector_type(4)));

__device__ __forceinline__ float waveSum(float v) {
#pragma unroll
    for (int m = 1; m < 64; m <<= 1) v += __shfl_xor(v, m, 64);
    return v;
}

// interleaved N-way wave sum: N independent butterfly chains for ILP
template <int N>
__device__ __forceinline__ void waveSumN(float* v) {
#pragma unroll
    for (int m = 1; m < 64; m <<= 1) {
#pragma unroll
        for (int j = 0; j < N; ++j) v[j] += __shfl_xor(v[j], m, 64);
    }
}

// ---------- packed-key top-k machinery ----------
// key = monotone(f32 sim) truncated to top-20 bits | (4095 - col).
__device__ __forceinline__ unsigned packKey(float v, int c) {
    unsigned u = __float_as_uint(v);
    u ^= (unsigned)((int)u >> 31) | 0x80000000u;   // monotone total order
    return (u & 0xFFFFF000u) | (unsigned)(4095 - c);
}

__device__ __forceinline__ void ceDesc(unsigned &a, unsigned &b) {
    unsigned mn = a > b ? b : a;
    a = a > b ? a : b;
    b = mn;
}

// merge partner's sorted-desc 4-list into mine (bitonic top-half + sort).
__device__ __forceinline__ void merge4(unsigned k[4],
                                       unsigned b0, unsigned b1,
                                       unsigned b2, unsigned b3) {
    k[0] = k[0] > b3 ? k[0] : b3;
    k[1] = k[1] > b2 ? k[1] : b2;
    k[2] = k[2] > b1 ? k[2] : b1;
    k[3] = k[3] > b0 ? k[3] : b0;
    ceDesc(k[0], k[2]); ceDesc(k[1], k[3]);
    ceDesc(k[0], k[1]); ceDesc(k[2], k[3]);
}

__device__ __forceinline__ void merge4Shfl(unsigned k[4], int m) {
    unsigned b0 = __shfl_xor(k[0], m, 64);
    unsigned b1 = __shfl_xor(k[1], m, 64);
    unsigned b2 = __shfl_xor(k[2], m, 64);
    unsigned b3 = __shfl_xor(k[3], m, 64);
    merge4(k, b0, b1, b2, b3);
}

// RNE float -> bf16 (returned as low-16 bits)
__device__ __forceinline__ unsigned bf16rne(float x) {
    unsigned u = __float_as_uint(x);
    return (u + 0x7FFFu + ((u >> 16) & 1u)) >> 16;
}

// ---------------- init: resid = x (qout derived as x - resid_final) ---------
__global__ void initK(const float* __restrict__ x, float* __restrict__ resid) {
    int i = blockIdx.x * blockDim.x + threadIdx.x;
    int stride = gridDim.x * blockDim.x;
    for (; i < QOUT_SZ; i += stride) resid[i] = x[i];
}

// ---------------- split fp32 -> bf16 hi/lo pair ----------------
__global__ void cvtSplitK(const float* __restrict__ src, short* __restrict__ hi,
                          short* __restrict__ lo, int n) {
    int i = (blockIdx.x * blockDim.x + threadIdx.x) * 4;
    int stride = gridDim.x * blockDim.x * 4;
    for (; i < n; i += stride) {
        float4 v = *(const float4*)&src[i];
        float vv[4] = {v.x, v.y, v.z, v.w};
        short hh[4], ll[4];
#pragma unroll
        for (int j = 0; j < 4; ++j) {
            unsigned hb = bf16rne(vv[j]);
            float hf = __uint_as_float(hb << 16);
            hh[j] = (short)hb;
            ll[j] = (short)bf16rne(vv[j] - hf);
        }
        *(short4*)&hi[i] = make_short4(hh[0], hh[1], hh[2], hh[3]);
        *(short4*)&lo[i] = make_short4(ll[0], ll[1], ll[2], ll[3]);
    }
}

// ------- implicit_cb = codebooks[q] @ weights[q]^T, bf16-split MFMA ----------
// Replaces fp32 VALU gemmCbK (~50 us/q at ~40 TF). 3-product bf16 emulation
// C ~= AhiBhi + AhiBlo + AloBhi (rel err ~1e-5 << tolerance).
// Geometry: 64x64 tile, 256 thr / 4 waves (2x2), 32x32 wave tile acc[2][2],
// BK=64, verified R4 XOR-swizzle gload_lds staging (rows == l15 mod 8).
__global__ __launch_bounds__(256)
void gemmCbMfmaK(const short* __restrict__ AHi, const short* __restrict__ ALo,
                 const short* __restrict__ BHi, const short* __restrict__ BLo,
                 float* __restrict__ out) {
    __shared__ short AH[64 * 64], AL[64 * 64];   // 16 KB
    __shared__ short BH[64 * 64], BL[64 * 64];   // 16 KB
    int t = threadIdx.x, w = t >> 6, lane = t & 63;
    int cBase = blockIdx.x * 64, dBase = blockIdx.y * 64;
    int mbase = (w & 1) * 32, nbase = (w >> 1) * 32;
    int l15 = lane & 15, quad = lane >> 4;

    f32x4 acc[2][2];
#pragma unroll
    for (int i = 0; i < 2; ++i)
#pragma unroll
        for (int j = 0; j < 2; ++j) acc[i][j] = (f32x4){0.f, 0.f, 0.f, 0.f};

    int rsub = lane >> 3;                 // 0..7 row within the 8-row group
    int swz = (lane & 7) ^ rsub;          // source 16B-chunk index

    for (int k0 = 0; k0 < DD; k0 += 64) {
        __syncthreads();
#pragma unroll
        for (int j = 0; j < 2; ++j) {
            int r0 = j * 32 + 8 * w;      // wave-uniform 8-row group base
            __builtin_amdgcn_global_load_lds(
                (const __attribute__((address_space(1))) void*)&AHi[(size_t)(cBase + r0 + rsub) * DD + k0 + swz * 8],
                (__attribute__((address_space(3))) void*)&AH[r0 * 64], 16, 0, 0);
            __builtin_amdgcn_global_load_lds(
                (const __attribute__((address_space(1))) void*)&ALo[(size_t)(cBase + r0 + rsub) * DD + k0 + swz * 8],
                (__attribute__((address_space(3))) void*)&AL[r0 * 64], 16, 0, 0);
            __builtin_amdgcn_global_load_lds(
                (const __attribute__((address_space(1))) void*)&BHi[(size_t)(dBase + r0 + rsub) * DD + k0 + swz * 8],
                (__attribute__((address_space(3))) void*)&BH[r0 * 64], 16, 0, 0);
            __builtin_amdgcn_global_load_lds(
                (const __attribute__((address_space(1))) void*)&BLo[(size_t)(dBase + r0 + rsub) * DD + k0 + swz * 8],
                (__attribute__((address_space(3))) void*)&BL[r0 * 64], 16, 0, 0);
        }
        __syncthreads();
#pragma unroll
        for (int kh = 0; kh < 2; ++kh) {
            int chunk = (kh * 4 + quad) ^ (l15 & 7);   // lds_row&7 == l15&7
            bf16x8 ah[2], al[2], bh[2], bl[2];
#pragma unroll
            for (int tm = 0; tm < 2; ++tm) {
                ah[tm] = *(const bf16x8*)&AH[(mbase + tm * 16 + l15) * 64 + chunk * 8];
                al[tm] = *(const bf16x8*)&AL[(mbase + tm * 16 + l15) * 64 + chunk * 8];
            }
#pragma unroll
            for (int tn = 0; tn < 2; ++tn) {
                bh[tn] = *(const bf16x8*)&BH[(nbase + tn * 16 + l15) * 64 + chunk * 8];
                bl[tn] = *(const bf16x8*)&BL[(nbase + tn * 16 + l15) * 64 + chunk * 8];
            }
#pragma unroll
            for (int tn = 0; tn < 2; ++tn)
#pragma unroll
                for (int tm = 0; tm < 2; ++tm) {
                    acc[tm][tn] = __builtin_amdgcn_mfma_f32_16x16x32_bf16(
                        ah[tm], bh[tn], acc[tm][tn], 0, 0, 0);
                    acc[tm][tn] = __builtin_amdgcn_mfma_f32_16x16x32_bf16(
                        ah[tm], bl[tn], acc[tm][tn], 0, 0, 0);
                    acc[tm][tn] = __builtin_amdgcn_mfma_f32_16x16x32_bf16(
                        al[tm], bh[tn], acc[tm][tn], 0, 0, 0);
                }
        }
    }

    // epilogue: D layout lane,reg r -> row = quad*4+r (in 16-tile), col = l15
#pragma unroll
    for (int tm = 0; tm < 2; ++tm)
#pragma unroll
        for (int tn = 0; tn < 2; ++tn)
#pragma unroll
            for (int r = 0; r < 4; ++r) {
                int row = cBase + mbase + tm * 16 + quad * 4 + r;
                int col = dBase + nbase + tn * 16 + l15;
                out[(size_t)row * DD + col] = acc[tm][tn][r];
            }
}

// ------- normalize cbn rows in place + emit f16 copy (one wave/row) ----------
__global__ void rowNormCvtK(float* __restrict__ buf, _Float16* __restrict__ bf16) {
    int wave = threadIdx.x >> 6, lane = threadIdx.x & 63;
    int row = blockIdx.x * 4 + wave;
    float* p = buf + (size_t)row * DD;
    float4 v0 = *(float4*)&p[lane * 8];
    float4 v1 = *(float4*)&p[lane * 8 + 4];
    float ss = v0.x*v0.x + v0.y*v0.y + v0.z*v0.z + v0.w*v0.w
             + v1.x*v1.x + v1.y*v1.y + v1.z*v1.z + v1.w*v1.w;
    ss = waveSum(ss);
    float nrm = fmaxf(sqrtf(ss), 1e-12f);
    float vals[8] = {v0.x/nrm, v0.y/nrm, v0.z/nrm, v0.w/nrm,
                     v1.x/nrm, v1.y/nrm, v1.z/nrm, v1.w/nrm};
    *(float4*)&p[lane * 8]     = make_float4(vals[0], vals[1], vals[2], vals[3]);
    *(float4*)&p[lane * 8 + 4] = make_float4(vals[4], vals[5], vals[6], vals[7]);
    f16x8 hv;
#pragma unroll
    for (int j = 0; j < 8; ++j) hv[j] = (_Float16)vals[j];
    *(f16x8*)&bf16[(size_t)row * DD + lane * 8] = hv;
}

// ------- resid row norms + f16 copy of RAW resid (q=0 only) ------------------
__global__ void residCvtK(const float* __restrict__ resid,
                          float* __restrict__ rnrm, _Float16* __restrict__ af16) {
    int wave = threadIdx.x >> 6, lane = threadIdx.x & 63;
    int row = blockIdx.x * 4 + wave;
    const float* p = resid + (size_t)row * DD;
    float4 v0 = *(const float4*)&p[lane * 8];
    float4 v1 = *(const float4*)&p[lane * 8 + 4];
    float vals[8] = {v0.x, v0.y, v0.z, v0.w, v1.x, v1.y, v1.z, v1.w};
    float ss = 0.f;
#pragma unroll
    for (int j = 0; j < 8; ++j) ss += vals[j] * vals[j];
    ss = waveSum(ss);
    if (lane == 0) rnrm[row] = fmaxf(sqrtf(ss), 1e-12f);
    f16x8 hv;
#pragma unroll
    for (int j = 0; j < 8; ++j) hv[j] = (_Float16)vals[j];
    *(f16x8*)&af16[(size_t)row * DD + lane * 8] = hv;
}

// ---------------- single-pass f16 MFMA sim GEMM + fused top-2 ----------------
// R5 verified build (112 us, MfmaUtil 27%): 128x128 tile, BK=64, 512 threads /
// 8 waves, 32x64 wave tiles, VGPR 44, LDS 32 KB, top-2-per-64-col-group keys.
// R7 post-mortem: zero-LDS direct loads regressed 3.3x (L1-thrash latency);
// R3/R6 fatter tiles regressed. This structure is the established optimum.
__global__ __launch_bounds__(512)
void simMfmaK(
    const _Float16* __restrict__ Af16, const _Float16* __restrict__ Bf16,
    unsigned* __restrict__ pk) {
    __shared__ _Float16 Alds[128 * 64];   // 16 KB
    __shared__ _Float16 Blds[128 * 64];   // 16 KB
    int t = threadIdx.x, w = t >> 6, lane = t & 63;
    int rowBase = blockIdx.x * 128;
    int cBase = blockIdx.y * 128;
    int mbase = (w & 3) * 32, nbase = (w >> 2) * 64;
    int l15 = lane & 15, quad = lane >> 4;

    f32x4 acc[2][4];
#pragma unroll
    for (int i = 0; i < 2; ++i)
#pragma unroll
        for (int j = 0; j < 4; ++j) acc[i][j] = (f32x4){0.f, 0.f, 0.f, 0.f};

    int rsub = lane >> 3;                 // 0..7 row within the wave's 8-row group
    int swz = (lane & 7) ^ rsub;          // source 16B-chunk index

    for (int k0 = 0; k0 < DD; k0 += 64) {
        __syncthreads();
#pragma unroll
        for (int j = 0; j < 2; ++j) {
            int rA = rowBase + j * 64 + 8 * w + rsub;
            int rB = cBase + j * 64 + 8 * w + rsub;
            __builtin_amdgcn_global_load_lds(
                (const __attribute__((address_space(1))) void*)&Af16[(size_t)rA * DD + k0 + swz * 8],
                (__attribute__((address_space(3))) void*)&Alds[(j * 64 + 8 * w) * 64], 16, 0, 0);
            __builtin_amdgcn_global_load_lds(
                (const __attribute__((address_space(1))) void*)&Bf16[(size_t)rB * DD + k0 + swz * 8],
                (__attribute__((address_space(3))) void*)&Blds[(j * 64 + 8 * w) * 64], 16, 0, 0);
        }
        __syncthreads();
#pragma unroll
        for (int kh = 0; kh < 2; ++kh) {
            int chunk = (kh * 4 + quad) ^ (l15 & 7);   // row&7 == l15&7 for all tiles
            f16x8 af[2];
#pragma unroll
            for (int tm = 0; tm < 2; ++tm)
                af[tm] = *(const f16x8*)&Alds[(mbase + tm * 16 + l15) * 64 + chunk * 8];
#pragma unroll
            for (int tn = 0; tn < 4; ++tn) {
                f16x8 bf = *(const f16x8*)&Blds[(nbase + tn * 16 + l15) * 64 + chunk * 8];
#pragma unroll
                for (int tm = 0; tm < 2; ++tm)
                    acc[tm][tn] = __builtin_amdgcn_mfma_f32_16x16x32_f16(
                        af[tm], bf, acc[tm][tn], 0, 0, 0);
            }
        }
    }

    // epilogue: per wave, top-2 per row over its 64 columns, packed keys.
    // D layout: lane,reg r -> row = quad*4+r (in 16-tile), col = l15
    int gkey = (cBase >> 6) + (w >> 2);   // global 64-col group index (0..63)
#pragma unroll
    for (int tm = 0; tm < 2; ++tm) {
#pragma unroll
        for (int r = 0; r < 4; ++r) {
            unsigned t0 = packKey(acc[tm][0][r], cBase + nbase + 0 * 16 + l15);
            unsigned t1 = packKey(acc[tm][1][r], cBase + nbase + 1 * 16 + l15);
            unsigned t2 = packKey(acc[tm][2][r], cBase + nbase + 2 * 16 + l15);
            unsigned t3 = packKey(acc[tm][3][r], cBase + nbase + 3 * 16 + l15);
            // per-lane sorted top-2 of 4 keys
            ceDesc(t0, t1); ceDesc(t2, t3);
            unsigned k0 = t0 > t2 ? t0 : t2;
            unsigned mn = t0 > t2 ? t2 : t0;
            unsigned mx = t1 > t3 ? t1 : t3;
            unsigned k1 = mn > mx ? mn : mx;
            // 16-lane butterfly merge of sorted pairs
#pragma unroll
            for (int m = 1; m < 16; m <<= 1) {
                unsigned b0 = __shfl_xor(k0, m, 64);
                unsigned b1 = __shfl_xor(k1, m, 64);
                unsigned m0 = k0 > b0 ? k0 : b0;
                unsigned n0 = k0 > b0 ? b0 : k0;
                unsigned m1 = k1 > b1 ? k1 : b1;
                k0 = m0;
                k1 = n0 > m1 ? n0 : m1;
            }
            if (l15 == 0) {
                int rowg = rowBase + mbase + tm * 16 + quad * 4 + r;
                *(uint2*)&pk[(size_t)rowg * 128 + gkey * 2] = make_uint2(k0, k1);
            }
        }
    }
}

// -------- finalize: merge group top-2s, fp32 rescore, rotation, resid update,
//          and emit next-q residual f16 + rnrm (fused residCvt) --------------
// dout accumulation removed (qout = x - resid_final, computed by qoutK).
__global__ void finalizeK(float* __restrict__ resid,
                          float* __restrict__ rnrm,
                          const float* __restrict__ cbn,
                          const unsigned* __restrict__ pk,
                          float* __restrict__ dout,
                          float* __restrict__ lossPart,
                          _Float16* __restrict__ af16, int q) {
    __shared__ float sL[4];
    int wave = threadIdx.x >> 6, lane = threadIdx.x & 63;
    int row = blockIdx.x * 4 + wave;
    float* xr = resid + (size_t)row * DD;
    float nrm = rnrm[row];
    float4 a0 = *(float4*)&xr[lane * 8];
    float4 a1 = *(float4*)&xr[lane * 8 + 4];
    float orig[8] = {a0.x,a0.y,a0.z,a0.w,a1.x,a1.y,a1.z,a1.w};
    float x[8];
#pragma unroll
    for (int j = 0; j < 8; ++j) x[j] = orig[j] / nrm;   // x_n per reference

    // 128 keys per row (64 groups x sorted top-2); lane l holds group l's pair
    uint2 kp = *(const uint2*)&pk[(size_t)row * 128 + lane * 2];
    unsigned k[4] = {kp.x, kp.y, 0u, 0u};   // sorted desc (zeros lose to real keys)
#pragma unroll
    for (int m = 1; m < 64; m <<= 1) merge4Shfl(k, m);
    int cand[4];
#pragma unroll
    for (int j = 0; j < 4; ++j)
        cand[j] = 4095 - (int)(__shfl(k[j], 0, 64) & 0xFFFu);

    // exact fp32 rescore of the 4 nominated candidates on the normalized row.
    float cv[4][8];
#pragma unroll
    for (int j = 0; j < 4; ++j) {
        const float* cbj = cbn + (size_t)cand[j] * DD;
        float4 c0 = *(const float4*)&cbj[lane * 8];
        float4 c1 = *(const float4*)&cbj[lane * 8 + 4];
        cv[j][0]=c0.x; cv[j][1]=c0.y; cv[j][2]=c0.z; cv[j][3]=c0.w;
        cv[j][4]=c1.x; cv[j][5]=c1.y; cv[j][6]=c1.z; cv[j][7]=c1.w;
    }
    float s[4];
#pragma unroll
    for (int j = 0; j < 4; ++j) {
        float acc = 0.f;
#pragma unroll
        for (int e = 0; e < 8; ++e) acc += x[e] * cv[j][e];
        s[j] = acc;
    }
    waveSumN<4>(s);
    float sBest = -3e38f; int idx = 0x7fffffff, sel = 0;
#pragma unroll
    for (int j = 0; j < 4; ++j) {
        if (s[j] > sBest || (s[j] == sBest && cand[j] < idx)) {
            sBest = s[j]; idx = cand[j]; sel = j;
        }
    }

    // winning row from registers (wave-uniform sel -> cndmask tree)
    float qv[8];
#pragma unroll
    for (int e = 0; e < 8; ++e)
        qv[e] = sel == 0 ? cv[0][e] : sel == 1 ? cv[1][e]
              : sel == 2 ? cv[2][e] : cv[3][e];

    float red3[3] = {0.f, 0.f, 0.f};   // ns2, nt2, lrow
#pragma unroll
    for (int j = 0; j < 8; ++j) {
        red3[0] += x[j] * x[j];
        red3[1] += qv[j] * qv[j];
        float d = x[j] - qv[j];
        red3[2] += d * d;
    }
    waveSumN<3>(red3);
    float ns = sqrtf(red3[0]), nt = sqrtf(red3[1]), lrow = red3[2];

    float u[8], qn[8], wv[8];
    float nw2 = 0.f;
#pragma unroll
    for (int j = 0; j < 8; ++j) {
        u[j] = x[j] / ns;
        qn[j] = qv[j] / nt;
        wv[j] = u[j] + qn[j];
        nw2 += wv[j] * wv[j];
    }
    nw2 = waveSum(nw2);
    float nw = fmaxf(sqrtf(nw2), 1e-12f);
    float red2[2] = {0.f, 0.f};        // dew, deu
#pragma unroll
    for (int j = 0; j < 8; ++j) {
        wv[j] = wv[j] / nw;
        red2[0] += x[j] * wv[j];
        red2[1] += x[j] * u[j];
    }
    waveSumN<2>(red2);
    float dew = red2[0], deu = red2[1];
    float scale = nt / ns;

    float r[8], nres[8];
    float ss = 0.f;
#pragma unroll
    for (int j = 0; j < 8; ++j) {
        r[j] = (x[j] - 2.0f * dew * wv[j] + 2.0f * deu * qn[j]) * scale;
        nres[j] = orig[j] - r[j];
        ss += nres[j] * nres[j];
    }

    // residual -= r ; emit f16 residual + next rnrm (fused residCvt)
    *(float4*)&xr[lane * 8]     = make_float4(nres[0], nres[1], nres[2], nres[3]);
    *(float4*)&xr[lane * 8 + 4] = make_float4(nres[4], nres[5], nres[6], nres[7]);
    ss = waveSum(ss);
    if (lane == 0) rnrm[row] = fmaxf(sqrtf(ss), 1e-12f);
    f16x8 hv;
#pragma unroll
    for (int j = 0; j < 8; ++j) hv[j] = (_Float16)nres[j];
    *(f16x8*)&af16[(size_t)row * DD + lane * 8] = hv;

    if (lane == 0) {
        dout[IDX_OFF + row * 4 + q] = (float)idx;
        sL[wave] = lrow;
    }
    __syncthreads();
    if (threadIdx.x == 0) {
        lossPart[(size_t)q * NBLK_FIN + blockIdx.x] =
            (sL[0] + sL[1] + sL[2] + sL[3]) * LOSS_COEF;
    }
}

// -------- qout = x - resid_final (replaces per-q dout accumulation) ----------
__global__ void qoutK(const float* __restrict__ x, const float* __restrict__ resid,
                      float* __restrict__ dout) {
    int i = blockIdx.x * blockDim.x + threadIdx.x;
    int stride = gridDim.x * blockDim.x;
    for (; i < QOUT_SZ; i += stride) dout[i] = x[i] - resid[i];
}

// -------- final loss reduce: one wave per q sums its 4096 block partials -----
__global__ void lossWriteK(const float* __restrict__ lossPart,
                           float* __restrict__ dout) {
    int q = threadIdx.x >> 6, lane = threadIdx.x & 63;
    float s = 0.f;
    for (int i = lane; i < NBLK_FIN; i += 64)
        s += lossPart[(size_t)q * NBLK_FIN + i];
    s = waveSum(s);
    if (lane == 0) dout[LOSS_OFF + q] = s;
}

extern "C" void kernel_launch(void* const* d_in, const int* in_sizes, int n_in,
                              void* d_out, int out_size, void* d_ws, size_t ws_size,
                              hipStream_t stream) {
    const float* x = (const float*)d_in[0];
    const float* codebooks = (const float*)d_in[1];
    const float* weights = (const float*)d_in[2];
    float* dout = (float*)d_out;
    float* w = (float*)d_ws;

    float* resid = w + WS_RESID;
    float* cbn   = w + WS_CBN;
    float* rnrm  = w + WS_RNRM;
    unsigned* pk = (unsigned*)(w + WS_PV);
    float* lossPart = w + WS_PI;
    _Float16* f16base = (_Float16*)(w + WS_F16);
    _Float16* Af16 = f16base + F16_A;
    _Float16* Bf16 = f16base + F16_B;
    // bf16 split buffers alias dead regions (see layout comment):
    short* cbHi = (short*)(w + WS_PV);          // 4.2 MB, aliases pk (dead here)
    short* cbLo = cbHi + (size_t)CC * DD;       // 4.2 MB, rest of pk region
    short* wHi  = (short*)(w + WS_PI + 32768);  // PI slack (lossPart uses 64 KB)
    short* wLo  = wHi + (size_t)DD * DD;

    initK<<<2048, 256, 0, stream>>>(x, resid);
    residCvtK<<<RR / 4, 256, 0, stream>>>(resid, rnrm, Af16);

    for (int q = 0; q < QQ; ++q) {
        cvtSplitK<<<512, 256, 0, stream>>>(codebooks + (size_t)q * CC * DD,
                                           cbHi, cbLo, CC * DD);
        cvtSplitK<<<128, 256, 0, stream>>>(weights + (size_t)q * DD * DD,
                                           wHi, wLo, DD * DD);
        gemmCbMfmaK<<<dim3(CC / 64, DD / 64), 256, 0, stream>>>(
            cbHi, cbLo, wHi, wLo, cbn);
        rowNormCvtK<<<CC / 4, 256, 0, stream>>>(cbn, Bf16);
        simMfmaK<<<dim3(RR / 128, CC / 128), 512, 0, stream>>>(Af16, Bf16, pk);
        finalizeK<<<RR / 4, 256, 0, stream>>>(resid, rnrm, cbn, pk,
                                              dout, lossPart, Af16, q);
    }
    qoutK<<<2048, 256, 0, stream>>>(x, resid, dout);
    lossWriteK<<<1, 256, 0, stream>>>(lossPart, dout);
}

// Round 12
// 773.672 us; speedup vs baseline: 2.3828x; 1.0061x over previous
//
#include <hip/hip_runtime.h>
#include <math.h>

// Problem constants
#define RR 16384        // B*N rows
#define DD 512          // feature dim
#define CC 4096         // codebook size
#define QQ 4            // num quantizers
#define QOUT_SZ (RR*DD)
#define IDX_OFF QOUT_SZ
#define LOSS_OFF (QOUT_SZ + RR*QQ)
#define LOSS_COEF (1.25f / 8388608.0f)
#define NBLK_FIN (RR/4)  // finalize blocks per dispatch (4096)

// Workspace layout (float offsets) -- IDENTICAL footprint to rounds 0-7
// (proven in-bounds; R8's 9 MB growth caused the container aborts).
// bf16 split buffers alias DEAD regions:
//   cbHi/cbLo (8.39 MB) -> pk region (dead between finalize(q) and simMfma(q))
//   wHi/wLo (1 MB) -> PI region slack (lossPart uses first 64 KB)
#define WS_RESID 0
#define WS_CBN   (RR*DD)                    // 8388608
#define WS_RNRM  (WS_CBN + CC*DD)           // 10485760
#define WS_PV    (WS_RNRM + RR)             // 10502144  (pk / cbHi+cbLo)
#define WS_PI    (WS_PV + RR*32*4)          // lossPart + wHi/wLo slack
#define WS_F16   (WS_PI + RR*32*4 + 4)      // 16B aligned
// f16 region (offsets in halves from WS_F16 base) -- original extent
#define F16_A 0
#define F16_B (RR*DD)

typedef _Float16 f16x8 __attribute__((ext_vector_type(8)));
typedef short bf16x8 __attribute__((ext_vector_type(8)));
typedef float f32x4 __attribute__((ext_vector_type(4)));

__device__ __forceinline__ float waveSum(float v) {
#pragma unroll
    for (int m = 1; m < 64; m <<= 1) v += __shfl_xor(v, m, 64);
    return v;
}

// interleaved N-way wave sum: N independent butterfly chains for ILP
template <int N>
__device__ __forceinline__ void waveSumN(float* v) {
#pragma unroll
    for (int m = 1; m < 64; m <<= 1) {
#pragma unroll
        for (int j = 0; j < N; ++j) v[j] += __shfl_xor(v[j], m, 64);
    }
}

// ---------- packed-key top-k machinery ----------
// key = monotone(f32 sim) truncated to top-20 bits | (4095 - col).
__device__ __forceinline__ unsigned packKey(float v, int c) {
    unsigned u = __float_as_uint(v);
    u ^= (unsigned)((int)u >> 31) | 0x80000000u;   // monotone total order
    return (u & 0xFFFFF000u) | (unsigned)(4095 - c);
}

__device__ __forceinline__ void ceDesc(unsigned &a, unsigned &b) {
    unsigned mn = a > b ? b : a;
    a = a > b ? a : b;
    b = mn;
}

// merge partner's sorted-desc 4-list into mine (bitonic top-half + sort).
__device__ __forceinline__ void merge4(unsigned k[4],
                                       unsigned b0, unsigned b1,
                                       unsigned b2, unsigned b3) {
    k[0] = k[0] > b3 ? k[0] : b3;
    k[1] = k[1] > b2 ? k[1] : b2;
    k[2] = k[2] > b1 ? k[2] : b1;
    k[3] = k[3] > b0 ? k[3] : b0;
    ceDesc(k[0], k[2]); ceDesc(k[1], k[3]);
    ceDesc(k[0], k[1]); ceDesc(k[2], k[3]);
}

__device__ __forceinline__ void merge4Shfl(unsigned k[4], int m) {
    unsigned b0 = __shfl_xor(k[0], m, 64);
    unsigned b1 = __shfl_xor(k[1], m, 64);
    unsigned b2 = __shfl_xor(k[2], m, 64);
    unsigned b3 = __shfl_xor(k[3], m, 64);
    merge4(k, b0, b1, b2, b3);
}

// RNE float -> bf16 (returned as low-16 bits)
__device__ __forceinline__ unsigned bf16rne(float x) {
    unsigned u = __float_as_uint(x);
    return (u + 0x7FFFu + ((u >> 16) & 1u)) >> 16;
}

// ---------------- init: resid = x (qout derived as x - resid_final) ---------
__global__ void initK(const float* __restrict__ x, float* __restrict__ resid) {
    int i = blockIdx.x * blockDim.x + threadIdx.x;
    int stride = gridDim.x * blockDim.x;
    for (; i < QOUT_SZ; i += stride) resid[i] = x[i];
}

// ---------------- split fp32 -> bf16 hi/lo pair ----------------
__global__ void cvtSplitK(const float* __restrict__ src, short* __restrict__ hi,
                          short* __restrict__ lo, int n) {
    int i = (blockIdx.x * blockDim.x + threadIdx.x) * 4;
    int stride = gridDim.x * blockDim.x * 4;
    for (; i < n; i += stride) {
        float4 v = *(const float4*)&src[i];
        float vv[4] = {v.x, v.y, v.z, v.w};
        short hh[4], ll[4];
#pragma unroll
        for (int j = 0; j < 4; ++j) {
            unsigned hb = bf16rne(vv[j]);
            float hf = __uint_as_float(hb << 16);
            hh[j] = (short)hb;
            ll[j] = (short)bf16rne(vv[j] - hf);
        }
        *(short4*)&hi[i] = make_short4(hh[0], hh[1], hh[2], hh[3]);
        *(short4*)&lo[i] = make_short4(ll[0], ll[1], ll[2], ll[3]);
    }
}

// ------- implicit_cb = codebooks[q] @ weights[q]^T, bf16-split MFMA ----------
// 3-product bf16 emulation C ~= AhiBhi + AhiBlo + AloBhi (rel err ~1e-5).
// Geometry: 64x64 tile, 256 thr / 4 waves (2x2), 32x32 wave tile acc[2][2],
// BK=64, verified XOR-swizzle gload_lds staging (rows == l15 mod 8).
__global__ __launch_bounds__(256)
void gemmCbMfmaK(const short* __restrict__ AHi, const short* __restrict__ ALo,
                 const short* __restrict__ BHi, const short* __restrict__ BLo,
                 float* __restrict__ out) {
    __shared__ short AH[64 * 64], AL[64 * 64];   // 16 KB
    __shared__ short BH[64 * 64], BL[64 * 64];   // 16 KB
    int t = threadIdx.x, w = t >> 6, lane = t & 63;
    int cBase = blockIdx.x * 64, dBase = blockIdx.y * 64;
    int mbase = (w & 1) * 32, nbase = (w >> 1) * 32;
    int l15 = lane & 15, quad = lane >> 4;

    f32x4 acc[2][2];
#pragma unroll
    for (int i = 0; i < 2; ++i)
#pragma unroll
        for (int j = 0; j < 2; ++j) acc[i][j] = (f32x4){0.f, 0.f, 0.f, 0.f};

    int rsub = lane >> 3;                 // 0..7 row within the 8-row group
    int swz = (lane & 7) ^ rsub;          // source 16B-chunk index

    for (int k0 = 0; k0 < DD; k0 += 64) {
        __syncthreads();
#pragma unroll
        for (int j = 0; j < 2; ++j) {
            int r0 = j * 32 + 8 * w;      // wave-uniform 8-row group base
            __builtin_amdgcn_global_load_lds(
                (const __attribute__((address_space(1))) void*)&AHi[(size_t)(cBase + r0 + rsub) * DD + k0 + swz * 8],
                (__attribute__((address_space(3))) void*)&AH[r0 * 64], 16, 0, 0);
            __builtin_amdgcn_global_load_lds(
                (const __attribute__((address_space(1))) void*)&ALo[(size_t)(cBase + r0 + rsub) * DD + k0 + swz * 8],
                (__attribute__((address_space(3))) void*)&AL[r0 * 64], 16, 0, 0);
            __builtin_amdgcn_global_load_lds(
                (const __attribute__((address_space(1))) void*)&BHi[(size_t)(dBase + r0 + rsub) * DD + k0 + swz * 8],
                (__attribute__((address_space(3))) void*)&BH[r0 * 64], 16, 0, 0);
            __builtin_amdgcn_global_load_lds(
                (const __attribute__((address_space(1))) void*)&BLo[(size_t)(dBase + r0 + rsub) * DD + k0 + swz * 8],
                (__attribute__((address_space(3))) void*)&BL[r0 * 64], 16, 0, 0);
        }
        __syncthreads();
#pragma unroll
        for (int kh = 0; kh < 2; ++kh) {
            int chunk = (kh * 4 + quad) ^ (l15 & 7);   // lds_row&7 == l15&7
            bf16x8 ah[2], al[2], bh[2], bl[2];
#pragma unroll
            for (int tm = 0; tm < 2; ++tm) {
                ah[tm] = *(const bf16x8*)&AH[(mbase + tm * 16 + l15) * 64 + chunk * 8];
                al[tm] = *(const bf16x8*)&AL[(mbase + tm * 16 + l15) * 64 + chunk * 8];
            }
#pragma unroll
            for (int tn = 0; tn < 2; ++tn) {
                bh[tn] = *(const bf16x8*)&BH[(nbase + tn * 16 + l15) * 64 + chunk * 8];
                bl[tn] = *(const bf16x8*)&BL[(nbase + tn * 16 + l15) * 64 + chunk * 8];
            }
#pragma unroll
            for (int tn = 0; tn < 2; ++tn)
#pragma unroll
                for (int tm = 0; tm < 2; ++tm) {
                    acc[tm][tn] = __builtin_amdgcn_mfma_f32_16x16x32_bf16(
                        ah[tm], bh[tn], acc[tm][tn], 0, 0, 0);
                    acc[tm][tn] = __builtin_amdgcn_mfma_f32_16x16x32_bf16(
                        ah[tm], bl[tn], acc[tm][tn], 0, 0, 0);
                    acc[tm][tn] = __builtin_amdgcn_mfma_f32_16x16x32_bf16(
                        al[tm], bh[tn], acc[tm][tn], 0, 0, 0);
                }
        }
    }

    // epilogue: D layout lane,reg r -> row = quad*4+r (in 16-tile), col = l15
#pragma unroll
    for (int tm = 0; tm < 2; ++tm)
#pragma unroll
        for (int tn = 0; tn < 2; ++tn)
#pragma unroll
            for (int r = 0; r < 4; ++r) {
                int row = cBase + mbase + tm * 16 + quad * 4 + r;
                int col = dBase + nbase + tn * 16 + l15;
                out[(size_t)row * DD + col] = acc[tm][tn][r];
            }
}

// ------- normalize cbn rows in place + emit f16 copy (one wave/row) ----------
__global__ void rowNormCvtK(float* __restrict__ buf, _Float16* __restrict__ bf16) {
    int wave = threadIdx.x >> 6, lane = threadIdx.x & 63;
    int row = blockIdx.x * 4 + wave;
    float* p = buf + (size_t)row * DD;
    float4 v0 = *(float4*)&p[lane * 8];
    float4 v1 = *(float4*)&p[lane * 8 + 4];
    float ss = v0.x*v0.x + v0.y*v0.y + v0.z*v0.z + v0.w*v0.w
             + v1.x*v1.x + v1.y*v1.y + v1.z*v1.z + v1.w*v1.w;
    ss = waveSum(ss);
    float nrm = fmaxf(sqrtf(ss), 1e-12f);
    float vals[8] = {v0.x/nrm, v0.y/nrm, v0.z/nrm, v0.w/nrm,
                     v1.x/nrm, v1.y/nrm, v1.z/nrm, v1.w/nrm};
    *(float4*)&p[lane * 8]     = make_float4(vals[0], vals[1], vals[2], vals[3]);
    *(float4*)&p[lane * 8 + 4] = make_float4(vals[4], vals[5], vals[6], vals[7]);
    f16x8 hv;
#pragma unroll
    for (int j = 0; j < 8; ++j) hv[j] = (_Float16)vals[j];
    *(f16x8*)&bf16[(size_t)row * DD + lane * 8] = hv;
}

// ------- resid row norms + f16 copy of RAW resid (q=0 only) ------------------
__global__ void residCvtK(const float* __restrict__ resid,
                          float* __restrict__ rnrm, _Float16* __restrict__ af16) {
    int wave = threadIdx.x >> 6, lane = threadIdx.x & 63;
    int row = blockIdx.x * 4 + wave;
    const float* p = resid + (size_t)row * DD;
    float4 v0 = *(const float4*)&p[lane * 8];
    float4 v1 = *(const float4*)&p[lane * 8 + 4];
    float vals[8] = {v0.x, v0.y, v0.z, v0.w, v1.x, v1.y, v1.z, v1.w};
    float ss = 0.f;
#pragma unroll
    for (int j = 0; j < 8; ++j) ss += vals[j] * vals[j];
    ss = waveSum(ss);
    if (lane == 0) rnrm[row] = fmaxf(sqrtf(ss), 1e-12f);
    f16x8 hv;
#pragma unroll
    for (int j = 0; j < 8; ++j) hv[j] = (_Float16)vals[j];
    *(f16x8*)&af16[(size_t)row * DD + lane * 8] = hv;
}

// ---------------- single-pass f16 MFMA sim GEMM + fused top-2 ----------------
// R11: counted-vmcnt double-buffer (T4) on the verified R5 geometry.
// Same 128x128 tile, BK=64, 8 waves, 32x64 wave tiles, top-2 epilogue.
// Change: LDS double-buffered (64 KB -> still 2 blocks/CU); per K-step the
// NEXT tile's 4 gload_lds are issued first, then `s_waitcnt vmcnt(4)` waits
// only for the CURRENT tile's loads (issued a full iteration ago -> latency
// already covered), with raw s_barrier (no compiler vmcnt(0) auto-drain).
// R2's dbuf failed at 96 KB/1 block-CU; m99/m100 show drain-to-0 dbuf ties;
// the counted wait is the untried quadrant (guide T4: counted-vs-drain0 is
// the entire 8-phase gain). sched_barrier(0) + "memory" clobbers fence
// compiler motion across the raw barriers (guide rule #18).
__global__ __launch_bounds__(512)
void simMfmaK(
    const _Float16* __restrict__ Af16, const _Float16* __restrict__ Bf16,
    unsigned* __restrict__ pk) {
    __shared__ _Float16 Alds[2][128 * 64];   // 32 KB
    __shared__ _Float16 Blds[2][128 * 64];   // 32 KB
    int t = threadIdx.x, w = t >> 6, lane = t & 63;
    int rowBase = blockIdx.x * 128;
    int cBase = blockIdx.y * 128;
    int mbase = (w & 3) * 32, nbase = (w >> 2) * 64;
    int l15 = lane & 15, quad = lane >> 4;

    f32x4 acc[2][4];
#pragma unroll
    for (int i = 0; i < 2; ++i)
#pragma unroll
        for (int j = 0; j < 4; ++j) acc[i][j] = (f32x4){0.f, 0.f, 0.f, 0.f};

    int rsub = lane >> 3;                 // 0..7 row within the wave's 8-row group
    int swz = (lane & 7) ^ rsub;          // source 16B-chunk index

    // stage tile tt into buffer b: 4 gload_lds per wave (2 A + 2 B)
#define SIM_STAGE(b, tt)                                                          \
    {                                                                             \
        int k0s = (tt) * 64;                                                      \
        _Pragma("unroll")                                                         \
        for (int j = 0; j < 2; ++j) {                                             \
            int rA = rowBase + j * 64 + 8 * w + rsub;                             \
            int rB = cBase + j * 64 + 8 * w + rsub;                               \
            __builtin_amdgcn_global_load_lds(                                     \
                (const __attribute__((address_space(1))) void*)&Af16[(size_t)rA * DD + k0s + swz * 8], \
                (__attribute__((address_space(3))) void*)&Alds[b][(j * 64 + 8 * w) * 64], 16, 0, 0);   \
            __builtin_amdgcn_global_load_lds(                                     \
                (const __attribute__((address_space(1))) void*)&Bf16[(size_t)rB * DD + k0s + swz * 8], \
                (__attribute__((address_space(3))) void*)&Blds[b][(j * 64 + 8 * w) * 64], 16, 0, 0);   \
        }                                                                         \
    }

    // prologue: tile 0 into buffer 0 (4 loads in flight)
    SIM_STAGE(0, 0);

#pragma unroll
    for (int tt = 0; tt < 8; ++tt) {
        int buf = tt & 1;
        if (tt < 7) {
            SIM_STAGE(buf ^ 1, tt + 1);                  // +4 loads (8 in flight)
            asm volatile("s_waitcnt vmcnt(4)" ::: "memory");  // tile tt landed
        } else {
            asm volatile("s_waitcnt vmcnt(0)" ::: "memory");  // final drain
        }
        __builtin_amdgcn_s_barrier();      // all waves' tile-tt loads done
        __builtin_amdgcn_sched_barrier(0); // pin ds_reads after the barrier
#pragma unroll
        for (int kh = 0; kh < 2; ++kh) {
            int chunk = (kh * 4 + quad) ^ (l15 & 7);   // row&7 == l15&7 for all tiles
            f16x8 af[2];
#pragma unroll
            for (int tm = 0; tm < 2; ++tm)
                af[tm] = *(const f16x8*)&Alds[buf][(mbase + tm * 16 + l15) * 64 + chunk * 8];
#pragma unroll
            for (int tn = 0; tn < 4; ++tn) {
                f16x8 bf = *(const f16x8*)&Blds[buf][(nbase + tn * 16 + l15) * 64 + chunk * 8];
#pragma unroll
                for (int tm = 0; tm < 2; ++tm)
                    acc[tm][tn] = __builtin_amdgcn_mfma_f32_16x16x32_f16(
                        af[tm], bf, acc[tm][tn], 0, 0, 0);
            }
        }
        __builtin_amdgcn_sched_barrier(0); // reads of buf complete before...
        asm volatile("" ::: "memory");
        __builtin_amdgcn_s_barrier();      // ...anyone restages into it
    }
#undef SIM_STAGE

    // epilogue: per wave, top-2 per row over its 64 columns, packed keys.
    // D layout: lane,reg r -> row = quad*4+r (in 16-tile), col = l15
    int gkey = (cBase >> 6) + (w >> 2);   // global 64-col group index (0..63)
#pragma unroll
    for (int tm = 0; tm < 2; ++tm) {
#pragma unroll
        for (int r = 0; r < 4; ++r) {
            unsigned t0 = packKey(acc[tm][0][r], cBase + nbase + 0 * 16 + l15);
            unsigned t1 = packKey(acc[tm][1][r], cBase + nbase + 1 * 16 + l15);
            unsigned t2 = packKey(acc[tm][2][r], cBase + nbase + 2 * 16 + l15);
            unsigned t3 = packKey(acc[tm][3][r], cBase + nbase + 3 * 16 + l15);
            // per-lane sorted top-2 of 4 keys
            ceDesc(t0, t1); ceDesc(t2, t3);
            unsigned k0 = t0 > t2 ? t0 : t2;
            unsigned mn = t0 > t2 ? t2 : t0;
            unsigned mx = t1 > t3 ? t1 : t3;
            unsigned k1 = mn > mx ? mn : mx;
            // 16-lane butterfly merge of sorted pairs
#pragma unroll
            for (int m = 1; m < 16; m <<= 1) {
                unsigned b0 = __shfl_xor(k0, m, 64);
                unsigned b1 = __shfl_xor(k1, m, 64);
                unsigned m0 = k0 > b0 ? k0 : b0;
                unsigned n0 = k0 > b0 ? b0 : k0;
                unsigned m1 = k1 > b1 ? k1 : b1;
                k0 = m0;
                k1 = n0 > m1 ? n0 : m1;
            }
            if (l15 == 0) {
                int rowg = rowBase + mbase + tm * 16 + quad * 4 + r;
                *(uint2*)&pk[(size_t)rowg * 128 + gkey * 2] = make_uint2(k0, k1);
            }
        }
    }
}

// -------- finalize: merge group top-2s, fp32 rescore, rotation, resid update,
//          and emit next-q residual f16 + rnrm (fused residCvt) --------------
// dout accumulation removed (qout = x - resid_final, computed by qoutK).
__global__ void finalizeK(float* __restrict__ resid,
                          float* __restrict__ rnrm,
                          const float* __restrict__ cbn,
                          const unsigned* __restrict__ pk,
                          float* __restrict__ dout,
                          float* __restrict__ lossPart,
                          _Float16* __restrict__ af16, int q) {
    __shared__ float sL[4];
    int wave = threadIdx.x >> 6, lane = threadIdx.x & 63;
    int row = blockIdx.x * 4 + wave;
    float* xr = resid + (size_t)row * DD;
    float nrm = rnrm[row];
    float4 a0 = *(float4*)&xr[lane * 8];
    float4 a1 = *(float4*)&xr[lane * 8 + 4];
    float orig[8] = {a0.x,a0.y,a0.z,a0.w,a1.x,a1.y,a1.z,a1.w};
    float x[8];
#pragma unroll
    for (int j = 0; j < 8; ++j) x[j] = orig[j] / nrm;   // x_n per reference

    // 128 keys per row (64 groups x sorted top-2); lane l holds group l's pair
    uint2 kp = *(const uint2*)&pk[(size_t)row * 128 + lane * 2];
    unsigned k[4] = {kp.x, kp.y, 0u, 0u};   // sorted desc (zeros lose to real keys)
#pragma unroll
    for (int m = 1; m < 64; m <<= 1) merge4Shfl(k, m);
    int cand[4];
#pragma unroll
    for (int j = 0; j < 4; ++j)
        cand[j] = 4095 - (int)(__shfl(k[j], 0, 64) & 0xFFFu);

    // exact fp32 rescore of the 4 nominated candidates on the normalized row.
    float cv[4][8];
#pragma unroll
    for (int j = 0; j < 4; ++j) {
        const float* cbj = cbn + (size_t)cand[j] * DD;
        float4 c0 = *(const float4*)&cbj[lane * 8];
        float4 c1 = *(const float4*)&cbj[lane * 8 + 4];
        cv[j][0]=c0.x; cv[j][1]=c0.y; cv[j][2]=c0.z; cv[j][3]=c0.w;
        cv[j][4]=c1.x; cv[j][5]=c1.y; cv[j][6]=c1.z; cv[j][7]=c1.w;
    }
    float s[4];
#pragma unroll
    for (int j = 0; j < 4; ++j) {
        float acc = 0.f;
#pragma unroll
        for (int e = 0; e < 8; ++e) acc += x[e] * cv[j][e];
        s[j] = acc;
    }
    waveSumN<4>(s);
    float sBest = -3e38f; int idx = 0x7fffffff, sel = 0;
#pragma unroll
    for (int j = 0; j < 4; ++j) {
        if (s[j] > sBest || (s[j] == sBest && cand[j] < idx)) {
            sBest = s[j]; idx = cand[j]; sel = j;
        }
    }

    // winning row from registers (wave-uniform sel -> cndmask tree)
    float qv[8];
#pragma unroll
    for (int e = 0; e < 8; ++e)
        qv[e] = sel == 0 ? cv[0][e] : sel == 1 ? cv[1][e]
              : sel == 2 ? cv[2][e] : cv[3][e];

    float red3[3] = {0.f, 0.f, 0.f};   // ns2, nt2, lrow
#pragma unroll
    for (int j = 0; j < 8; ++j) {
        red3[0] += x[j] * x[j];
        red3[1] += qv[j] * qv[j];
        float d = x[j] - qv[j];
        red3[2] += d * d;
    }
    waveSumN<3>(red3);
    float ns = sqrtf(red3[0]), nt = sqrtf(red3[1]), lrow = red3[2];

    float u[8], qn[8], wv[8];
    float nw2 = 0.f;
#pragma unroll
    for (int j = 0; j < 8; ++j) {
        u[j] = x[j] / ns;
        qn[j] = qv[j] / nt;
        wv[j] = u[j] + qn[j];
        nw2 += wv[j] * wv[j];
    }
    nw2 = waveSum(nw2);
    float nw = fmaxf(sqrtf(nw2), 1e-12f);
    float red2[2] = {0.f, 0.f};        // dew, deu
#pragma unroll
    for (int j = 0; j < 8; ++j) {
        wv[j] = wv[j] / nw;
        red2[0] += x[j] * wv[j];
        red2[1] += x[j] * u[j];
    }
    waveSumN<2>(red2);
    float dew = red2[0], deu = red2[1];
    float scale = nt / ns;

    float r[8], nres[8];
    float ss = 0.f;
#pragma unroll
    for (int j = 0; j < 8; ++j) {
        r[j] = (x[j] - 2.0f * dew * wv[j] + 2.0f * deu * qn[j]) * scale;
        nres[j] = orig[j] - r[j];
        ss += nres[j] * nres[j];
    }

    // residual -= r ; emit f16 residual + next rnrm (fused residCvt)
    *(float4*)&xr[lane * 8]     = make_float4(nres[0], nres[1], nres[2], nres[3]);
    *(float4*)&xr[lane * 8 + 4] = make_float4(nres[4], nres[5], nres[6], nres[7]);
    ss = waveSum(ss);
    if (lane == 0) rnrm[row] = fmaxf(sqrtf(ss), 1e-12f);
    f16x8 hv;
#pragma unroll
    for (int j = 0; j < 8; ++j) hv[j] = (_Float16)nres[j];
    *(f16x8*)&af16[(size_t)row * DD + lane * 8] = hv;

    if (lane == 0) {
        dout[IDX_OFF + row * 4 + q] = (float)idx;
        sL[wave] = lrow;
    }
    __syncthreads();
    if (threadIdx.x == 0) {
        lossPart[(size_t)q * NBLK_FIN + blockIdx.x] =
            (sL[0] + sL[1] + sL[2] + sL[3]) * LOSS_COEF;
    }
}

// -------- qout = x - resid_final (replaces per-q dout accumulation) ----------
__global__ void qoutK(const float* __restrict__ x, const float* __restrict__ resid,
                      float* __restrict__ dout) {
    int i = blockIdx.x * blockDim.x + threadIdx.x;
    int stride = gridDim.x * blockDim.x;
    for (; i < QOUT_SZ; i += stride) dout[i] = x[i] - resid[i];
}

// -------- final loss reduce: one wave per q sums its 4096 block partials -----
__global__ void lossWriteK(const float* __restrict__ lossPart,
                           float* __restrict__ dout) {
    int q = threadIdx.x >> 6, lane = threadIdx.x & 63;
    float s = 0.f;
    for (int i = lane; i < NBLK_FIN; i += 64)
        s += lossPart[(size_t)q * NBLK_FIN + i];
    s = waveSum(s);
    if (lane == 0) dout[LOSS_OFF + q] = s;
}

extern "C" void kernel_launch(void* const* d_in, const int* in_sizes, int n_in,
                              void* d_out, int out_size, void* d_ws, size_t ws_size,
                              hipStream_t stream) {
    const float* x = (const float*)d_in[0];
    const float* codebooks = (const float*)d_in[1];
    const float* weights = (const float*)d_in[2];
    float* dout = (float*)d_out;
    float* w = (float*)d_ws;

    float* resid = w + WS_RESID;
    float* cbn   = w + WS_CBN;
    float* rnrm  = w + WS_RNRM;
    unsigned* pk = (unsigned*)(w + WS_PV);
    float* lossPart = w + WS_PI;
    _Float16* f16base = (_Float16*)(w + WS_F16);
    _Float16* Af16 = f16base + F16_A;
    _Float16* Bf16 = f16base + F16_B;
    // bf16 split buffers alias dead regions (see layout comment):
    short* cbHi = (short*)(w + WS_PV);          // 4.2 MB, aliases pk (dead here)
    short* cbLo = cbHi + (size_t)CC * DD;       // 4.2 MB, rest of pk region
    short* wHi  = (short*)(w + WS_PI + 32768);  // PI slack (lossPart uses 64 KB)
    short* wLo  = wHi + (size_t)DD * DD;

    initK<<<2048, 256, 0, stream>>>(x, resid);
    residCvtK<<<RR / 4, 256, 0, stream>>>(resid, rnrm, Af16);

    for (int q = 0; q < QQ; ++q) {
        cvtSplitK<<<512, 256, 0, stream>>>(codebooks + (size_t)q * CC * DD,
                                           cbHi, cbLo, CC * DD);
        cvtSplitK<<<128, 256, 0, stream>>>(weights + (size_t)q * DD * DD,
                                           wHi, wLo, DD * DD);
        gemmCbMfmaK<<<dim3(CC / 64, DD / 64), 256, 0, stream>>>(
            cbHi, cbLo, wHi, wLo, cbn);
        rowNormCvtK<<<CC / 4, 256, 0, stream>>>(cbn, Bf16);
        simMfmaK<<<dim3(RR / 128, CC / 128), 512, 0, stream>>>(Af16, Bf16, pk);
        finalizeK<<<RR / 4, 256, 0, stream>>>(resid, rnrm, cbn, pk,
                                              dout, lossPart, Af16, q);
    }
    qoutK<<<2048, 256, 0, stream>>>(x, resid, dout);
    lossWriteK<<<1, 256, 0, stream>>>(lossPart, dout);
}

// Round 13
// 752.491 us; speedup vs baseline: 2.4499x; 1.0281x over previous
//
#include <hip/hip_runtime.h>
#include <math.h>

// Problem constants
#define RR 16384        // B*N rows
#define DD 512          // feature dim
#define CC 4096         // codebook size
#define QQ 4            // num quantizers
#define QOUT_SZ (RR*DD)
#define IDX_OFF QOUT_SZ
#define LOSS_OFF (QOUT_SZ + RR*QQ)
#define LOSS_COEF (1.25f / 8388608.0f)
#define NBLK_FIN (RR/4)  // finalize blocks per dispatch (4096)

// Workspace layout (float offsets) -- IDENTICAL footprint to rounds 0-7
// (proven in-bounds; R8's 9 MB growth caused the container aborts).
// bf16 split buffers alias DEAD regions:
//   cbHi/cbLo (8.39 MB) -> pk region (dead between finalize(q) and simMfma(q))
//   wHi/wLo (1 MB) -> PI region slack (lossPart uses first 64 KB)
#define WS_RESID 0
#define WS_CBN   (RR*DD)                    // 8388608
#define WS_RNRM  (WS_CBN + CC*DD)           // 10485760
#define WS_PV    (WS_RNRM + RR)             // 10502144  (pk / cbHi+cbLo)
#define WS_PI    (WS_PV + RR*32*4)          // lossPart + wHi/wLo slack
#define WS_F16   (WS_PI + RR*32*4 + 4)      // 16B aligned
// f16 region (offsets in halves from WS_F16 base) -- original extent
#define F16_A 0
#define F16_B (RR*DD)

typedef _Float16 f16x8 __attribute__((ext_vector_type(8)));
typedef short bf16x8 __attribute__((ext_vector_type(8)));
typedef float f32x4 __attribute__((ext_vector_type(4)));

__device__ __forceinline__ float waveSum(float v) {
#pragma unroll
    for (int m = 1; m < 64; m <<= 1) v += __shfl_xor(v, m, 64);
    return v;
}

// interleaved N-way wave sum: N independent butterfly chains for ILP
template <int N>
__device__ __forceinline__ void waveSumN(float* v) {
#pragma unroll
    for (int m = 1; m < 64; m <<= 1) {
#pragma unroll
        for (int j = 0; j < N; ++j) v[j] += __shfl_xor(v[j], m, 64);
    }
}

// ---------- packed-key top-k machinery ----------
// key = monotone(f32 sim) truncated to top-20 bits | (4095 - col).
__device__ __forceinline__ unsigned packKey(float v, int c) {
    unsigned u = __float_as_uint(v);
    u ^= (unsigned)((int)u >> 31) | 0x80000000u;   // monotone total order
    return (u & 0xFFFFF000u) | (unsigned)(4095 - c);
}

__device__ __forceinline__ void ceDesc(unsigned &a, unsigned &b) {
    unsigned mn = a > b ? b : a;
    a = a > b ? a : b;
    b = mn;
}

// merge partner's sorted-desc 4-list into mine (bitonic top-half + sort).
__device__ __forceinline__ void merge4(unsigned k[4],
                                       unsigned b0, unsigned b1,
                                       unsigned b2, unsigned b3) {
    k[0] = k[0] > b3 ? k[0] : b3;
    k[1] = k[1] > b2 ? k[1] : b2;
    k[2] = k[2] > b1 ? k[2] : b1;
    k[3] = k[3] > b0 ? k[3] : b0;
    ceDesc(k[0], k[2]); ceDesc(k[1], k[3]);
    ceDesc(k[0], k[1]); ceDesc(k[2], k[3]);
}

__device__ __forceinline__ void merge4Shfl(unsigned k[4], int m) {
    unsigned b0 = __shfl_xor(k[0], m, 64);
    unsigned b1 = __shfl_xor(k[1], m, 64);
    unsigned b2 = __shfl_xor(k[2], m, 64);
    unsigned b3 = __shfl_xor(k[3], m, 64);
    merge4(k, b0, b1, b2, b3);
}

// RNE float -> bf16 (returned as low-16 bits)
__device__ __forceinline__ unsigned bf16rne(float x) {
    unsigned u = __float_as_uint(x);
    return (u + 0x7FFFu + ((u >> 16) & 1u)) >> 16;
}

// ---------------- init: resid = x (qout derived as x - resid_final) ---------
__global__ void initK(const float* __restrict__ x, float* __restrict__ resid) {
    int i = blockIdx.x * blockDim.x + threadIdx.x;
    int stride = gridDim.x * blockDim.x;
    for (; i < QOUT_SZ; i += stride) resid[i] = x[i];
}

// ---------------- split fp32 -> bf16 hi/lo pair ----------------
__global__ void cvtSplitK(const float* __restrict__ src, short* __restrict__ hi,
                          short* __restrict__ lo, int n) {
    int i = (blockIdx.x * blockDim.x + threadIdx.x) * 4;
    int stride = gridDim.x * blockDim.x * 4;
    for (; i < n; i += stride) {
        float4 v = *(const float4*)&src[i];
        float vv[4] = {v.x, v.y, v.z, v.w};
        short hh[4], ll[4];
#pragma unroll
        for (int j = 0; j < 4; ++j) {
            unsigned hb = bf16rne(vv[j]);
            float hf = __uint_as_float(hb << 16);
            hh[j] = (short)hb;
            ll[j] = (short)bf16rne(vv[j] - hf);
        }
        *(short4*)&hi[i] = make_short4(hh[0], hh[1], hh[2], hh[3]);
        *(short4*)&lo[i] = make_short4(ll[0], ll[1], ll[2], ll[3]);
    }
}

// ------- implicit_cb = codebooks[q] @ weights[q]^T, bf16-split MFMA ----------
// 3-product bf16 emulation C ~= AhiBhi + AhiBlo + AloBhi (rel err ~1e-5).
// Geometry: 64x64 tile, 256 thr / 4 waves (2x2), 32x32 wave tile acc[2][2],
// BK=64, verified XOR-swizzle gload_lds staging (rows == l15 mod 8).
__global__ __launch_bounds__(256)
void gemmCbMfmaK(const short* __restrict__ AHi, const short* __restrict__ ALo,
                 const short* __restrict__ BHi, const short* __restrict__ BLo,
                 float* __restrict__ out) {
    __shared__ short AH[64 * 64], AL[64 * 64];   // 16 KB
    __shared__ short BH[64 * 64], BL[64 * 64];   // 16 KB
    int t = threadIdx.x, w = t >> 6, lane = t & 63;
    int cBase = blockIdx.x * 64, dBase = blockIdx.y * 64;
    int mbase = (w & 1) * 32, nbase = (w >> 1) * 32;
    int l15 = lane & 15, quad = lane >> 4;

    f32x4 acc[2][2];
#pragma unroll
    for (int i = 0; i < 2; ++i)
#pragma unroll
        for (int j = 0; j < 2; ++j) acc[i][j] = (f32x4){0.f, 0.f, 0.f, 0.f};

    int rsub = lane >> 3;                 // 0..7 row within the 8-row group
    int swz = (lane & 7) ^ rsub;          // source 16B-chunk index

    for (int k0 = 0; k0 < DD; k0 += 64) {
        __syncthreads();
#pragma unroll
        for (int j = 0; j < 2; ++j) {
            int r0 = j * 32 + 8 * w;      // wave-uniform 8-row group base
            __builtin_amdgcn_global_load_lds(
                (const __attribute__((address_space(1))) void*)&AHi[(size_t)(cBase + r0 + rsub) * DD + k0 + swz * 8],
                (__attribute__((address_space(3))) void*)&AH[r0 * 64], 16, 0, 0);
            __builtin_amdgcn_global_load_lds(
                (const __attribute__((address_space(1))) void*)&ALo[(size_t)(cBase + r0 + rsub) * DD + k0 + swz * 8],
                (__attribute__((address_space(3))) void*)&AL[r0 * 64], 16, 0, 0);
            __builtin_amdgcn_global_load_lds(
                (const __attribute__((address_space(1))) void*)&BHi[(size_t)(dBase + r0 + rsub) * DD + k0 + swz * 8],
                (__attribute__((address_space(3))) void*)&BH[r0 * 64], 16, 0, 0);
            __builtin_amdgcn_global_load_lds(
                (const __attribute__((address_space(1))) void*)&BLo[(size_t)(dBase + r0 + rsub) * DD + k0 + swz * 8],
                (__attribute__((address_space(3))) void*)&BL[r0 * 64], 16, 0, 0);
        }
        __syncthreads();
#pragma unroll
        for (int kh = 0; kh < 2; ++kh) {
            int chunk = (kh * 4 + quad) ^ (l15 & 7);   // lds_row&7 == l15&7
            bf16x8 ah[2], al[2], bh[2], bl[2];
#pragma unroll
            for (int tm = 0; tm < 2; ++tm) {
                ah[tm] = *(const bf16x8*)&AH[(mbase + tm * 16 + l15) * 64 + chunk * 8];
                al[tm] = *(const bf16x8*)&AL[(mbase + tm * 16 + l15) * 64 + chunk * 8];
            }
#pragma unroll
            for (int tn = 0; tn < 2; ++tn) {
                bh[tn] = *(const bf16x8*)&BH[(nbase + tn * 16 + l15) * 64 + chunk * 8];
                bl[tn] = *(const bf16x8*)&BL[(nbase + tn * 16 + l15) * 64 + chunk * 8];
            }
#pragma unroll
            for (int tn = 0; tn < 2; ++tn)
#pragma unroll
                for (int tm = 0; tm < 2; ++tm) {
                    acc[tm][tn] = __builtin_amdgcn_mfma_f32_16x16x32_bf16(
                        ah[tm], bh[tn], acc[tm][tn], 0, 0, 0);
                    acc[tm][tn] = __builtin_amdgcn_mfma_f32_16x16x32_bf16(
                        ah[tm], bl[tn], acc[tm][tn], 0, 0, 0);
                    acc[tm][tn] = __builtin_amdgcn_mfma_f32_16x16x32_bf16(
                        al[tm], bh[tn], acc[tm][tn], 0, 0, 0);
                }
        }
    }

    // epilogue: D layout lane,reg r -> row = quad*4+r (in 16-tile), col = l15
#pragma unroll
    for (int tm = 0; tm < 2; ++tm)
#pragma unroll
        for (int tn = 0; tn < 2; ++tn)
#pragma unroll
            for (int r = 0; r < 4; ++r) {
                int row = cBase + mbase + tm * 16 + quad * 4 + r;
                int col = dBase + nbase + tn * 16 + l15;
                out[(size_t)row * DD + col] = acc[tm][tn][r];
            }
}

// ------- normalize cbn rows in place + emit f16 copy (one wave/row) ----------
__global__ void rowNormCvtK(float* __restrict__ buf, _Float16* __restrict__ bf16) {
    int wave = threadIdx.x >> 6, lane = threadIdx.x & 63;
    int row = blockIdx.x * 4 + wave;
    float* p = buf + (size_t)row * DD;
    float4 v0 = *(float4*)&p[lane * 8];
    float4 v1 = *(float4*)&p[lane * 8 + 4];
    float ss = v0.x*v0.x + v0.y*v0.y + v0.z*v0.z + v0.w*v0.w
             + v1.x*v1.x + v1.y*v1.y + v1.z*v1.z + v1.w*v1.w;
    ss = waveSum(ss);
    float nrm = fmaxf(sqrtf(ss), 1e-12f);
    float vals[8] = {v0.x/nrm, v0.y/nrm, v0.z/nrm, v0.w/nrm,
                     v1.x/nrm, v1.y/nrm, v1.z/nrm, v1.w/nrm};
    *(float4*)&p[lane * 8]     = make_float4(vals[0], vals[1], vals[2], vals[3]);
    *(float4*)&p[lane * 8 + 4] = make_float4(vals[4], vals[5], vals[6], vals[7]);
    f16x8 hv;
#pragma unroll
    for (int j = 0; j < 8; ++j) hv[j] = (_Float16)vals[j];
    *(f16x8*)&bf16[(size_t)row * DD + lane * 8] = hv;
}

// ------- resid row norms + f16 copy of RAW resid (q=0 only) ------------------
__global__ void residCvtK(const float* __restrict__ resid,
                          float* __restrict__ rnrm, _Float16* __restrict__ af16) {
    int wave = threadIdx.x >> 6, lane = threadIdx.x & 63;
    int row = blockIdx.x * 4 + wave;
    const float* p = resid + (size_t)row * DD;
    float4 v0 = *(const float4*)&p[lane * 8];
    float4 v1 = *(const float4*)&p[lane * 8 + 4];
    float vals[8] = {v0.x, v0.y, v0.z, v0.w, v1.x, v1.y, v1.z, v1.w};
    float ss = 0.f;
#pragma unroll
    for (int j = 0; j < 8; ++j) ss += vals[j] * vals[j];
    ss = waveSum(ss);
    if (lane == 0) rnrm[row] = fmaxf(sqrtf(ss), 1e-12f);
    f16x8 hv;
#pragma unroll
    for (int j = 0; j < 8; ++j) hv[j] = (_Float16)vals[j];
    *(f16x8*)&af16[(size_t)row * DD + lane * 8] = hv;
}

// ---------------- single-pass f16 MFMA sim GEMM + fused top-2 ----------------
// R12: ONE barrier per K-step (guide T3 minimum 2-phase template) on R11's
// counted-vmcnt dbuf. Schedule: stage(t+1 into buf^1) -> compute(buf) ->
// vmcnt(0)+barrier. The end-of-step barrier guarantees all waves finished
// compute(buf) before anyone (at t+1) restages into buf; vmcnt(0) is covered
// by ~600 cyc of compute since the loads were issued at the top of the step.
// 9 barriers/block vs R11's 17. Geometry unchanged (128x128, BK=64, 8 waves,
// 32x64 wave tiles, 64 KB dbuf LDS, top-2-per-64-col-group epilogue).
__global__ __launch_bounds__(512)
void simMfmaK(
    const _Float16* __restrict__ Af16, const _Float16* __restrict__ Bf16,
    unsigned* __restrict__ pk) {
    __shared__ _Float16 Alds[2][128 * 64];   // 32 KB
    __shared__ _Float16 Blds[2][128 * 64];   // 32 KB
    int t = threadIdx.x, w = t >> 6, lane = t & 63;
    int rowBase = blockIdx.x * 128;
    int cBase = blockIdx.y * 128;
    int mbase = (w & 3) * 32, nbase = (w >> 2) * 64;
    int l15 = lane & 15, quad = lane >> 4;

    f32x4 acc[2][4];
#pragma unroll
    for (int i = 0; i < 2; ++i)
#pragma unroll
        for (int j = 0; j < 4; ++j) acc[i][j] = (f32x4){0.f, 0.f, 0.f, 0.f};

    int rsub = lane >> 3;                 // 0..7 row within the wave's 8-row group
    int swz = (lane & 7) ^ rsub;          // source 16B-chunk index

    // stage tile tt into buffer b: 4 gload_lds per wave (2 A + 2 B)
#define SIM_STAGE(b, tt)                                                          \
    {                                                                             \
        int k0s = (tt) * 64;                                                      \
        _Pragma("unroll")                                                         \
        for (int j = 0; j < 2; ++j) {                                             \
            int rA = rowBase + j * 64 + 8 * w + rsub;                             \
            int rB = cBase + j * 64 + 8 * w + rsub;                               \
            __builtin_amdgcn_global_load_lds(                                     \
                (const __attribute__((address_space(1))) void*)&Af16[(size_t)rA * DD + k0s + swz * 8], \
                (__attribute__((address_space(3))) void*)&Alds[b][(j * 64 + 8 * w) * 64], 16, 0, 0);   \
            __builtin_amdgcn_global_load_lds(                                     \
                (const __attribute__((address_space(1))) void*)&Bf16[(size_t)rB * DD + k0s + swz * 8], \
                (__attribute__((address_space(3))) void*)&Blds[b][(j * 64 + 8 * w) * 64], 16, 0, 0);   \
        }                                                                         \
    }

    // prologue: tile 0 into buffer 0, drain, barrier
    SIM_STAGE(0, 0);
    asm volatile("s_waitcnt vmcnt(0)" ::: "memory");
    __builtin_amdgcn_s_barrier();
    __builtin_amdgcn_sched_barrier(0);

#pragma unroll
    for (int tt = 0; tt < 8; ++tt) {
        int buf = tt & 1;
        if (tt < 7) SIM_STAGE(buf ^ 1, tt + 1);   // issue next tile's loads
#pragma unroll
        for (int kh = 0; kh < 2; ++kh) {
            int chunk = (kh * 4 + quad) ^ (l15 & 7);   // row&7 == l15&7 for all tiles
            f16x8 af[2];
#pragma unroll
            for (int tm = 0; tm < 2; ++tm)
                af[tm] = *(const f16x8*)&Alds[buf][(mbase + tm * 16 + l15) * 64 + chunk * 8];
#pragma unroll
            for (int tn = 0; tn < 4; ++tn) {
                f16x8 bf = *(const f16x8*)&Blds[buf][(nbase + tn * 16 + l15) * 64 + chunk * 8];
#pragma unroll
                for (int tm = 0; tm < 2; ++tm)
                    acc[tm][tn] = __builtin_amdgcn_mfma_f32_16x16x32_f16(
                        af[tm], bf, acc[tm][tn], 0, 0, 0);
            }
        }
        if (tt < 7) {
            __builtin_amdgcn_sched_barrier(0);          // pin this step's ds_reads
            asm volatile("s_waitcnt vmcnt(0)" ::: "memory");  // tile tt+1 landed
            __builtin_amdgcn_s_barrier();               // all done reading buf
            __builtin_amdgcn_sched_barrier(0);          // pin next ds_reads after
        }
    }
#undef SIM_STAGE

    // epilogue: per wave, top-2 per row over its 64 columns, packed keys.
    // D layout: lane,reg r -> row = quad*4+r (in 16-tile), col = l15
    int gkey = (cBase >> 6) + (w >> 2);   // global 64-col group index (0..63)
#pragma unroll
    for (int tm = 0; tm < 2; ++tm) {
#pragma unroll
        for (int r = 0; r < 4; ++r) {
            unsigned t0 = packKey(acc[tm][0][r], cBase + nbase + 0 * 16 + l15);
            unsigned t1 = packKey(acc[tm][1][r], cBase + nbase + 1 * 16 + l15);
            unsigned t2 = packKey(acc[tm][2][r], cBase + nbase + 2 * 16 + l15);
            unsigned t3 = packKey(acc[tm][3][r], cBase + nbase + 3 * 16 + l15);
            // per-lane sorted top-2 of 4 keys
            ceDesc(t0, t1); ceDesc(t2, t3);
            unsigned k0 = t0 > t2 ? t0 : t2;
            unsigned mn = t0 > t2 ? t2 : t0;
            unsigned mx = t1 > t3 ? t1 : t3;
            unsigned k1 = mn > mx ? mn : mx;
            // 16-lane butterfly merge of sorted pairs
#pragma unroll
            for (int m = 1; m < 16; m <<= 1) {
                unsigned b0 = __shfl_xor(k0, m, 64);
                unsigned b1 = __shfl_xor(k1, m, 64);
                unsigned m0 = k0 > b0 ? k0 : b0;
                unsigned n0 = k0 > b0 ? b0 : k0;
                unsigned m1 = k1 > b1 ? k1 : b1;
                k0 = m0;
                k1 = n0 > m1 ? n0 : m1;
            }
            if (l15 == 0) {
                int rowg = rowBase + mbase + tm * 16 + quad * 4 + r;
                *(uint2*)&pk[(size_t)rowg * 128 + gkey * 2] = make_uint2(k0, k1);
            }
        }
    }
}

// -------- finalize: merge group top-2s, fp32 rescore, resid update -----------
// R12: rotation-identity simplification. For unit-norm src and tgt (x_n is
// orig/||orig||, quant is a rowNorm'd codebook row), rotate_to's forward pass
// is EXACTLY the target: w=(u+q)/||u+q||, u.w=(1+u.q)/||u+q||, 2(u.w)w = u+q,
// r = u-(u+q)+2q = q, scale = nt/ns = 1. The reference's long computation
// differs only by ~1e-7 fp noise (absmax invariant at 2^-9 across 12 rounds).
// So: r = cbn[idx]; resid -= cbn[idx]; lrow = ||x-q||^2 = 2 - 2*sim.
// Rescore uses unnormalized orig (argmax invariant under positive scaling);
// sim = sBest/nrm. Kernel collapses to gather + rescore + subtract + write:
// 3 shfl-reduction chains (merge, rescore, ss) instead of 5.
__global__ void finalizeK(float* __restrict__ resid,
                          float* __restrict__ rnrm,
                          const float* __restrict__ cbn,
                          const unsigned* __restrict__ pk,
                          float* __restrict__ dout,
                          float* __restrict__ lossPart,
                          _Float16* __restrict__ af16, int q) {
    __shared__ float sL[4];
    int wave = threadIdx.x >> 6, lane = threadIdx.x & 63;
    int row = blockIdx.x * 4 + wave;
    float* xr = resid + (size_t)row * DD;
    float nrm = rnrm[row];
    float4 a0 = *(float4*)&xr[lane * 8];
    float4 a1 = *(float4*)&xr[lane * 8 + 4];
    float orig[8] = {a0.x,a0.y,a0.z,a0.w,a1.x,a1.y,a1.z,a1.w};

    // 128 keys per row (64 groups x sorted top-2); lane l holds group l's pair
    uint2 kp = *(const uint2*)&pk[(size_t)row * 128 + lane * 2];
    unsigned k[4] = {kp.x, kp.y, 0u, 0u};   // sorted desc (zeros lose to real keys)
#pragma unroll
    for (int m = 1; m < 64; m <<= 1) merge4Shfl(k, m);
    int cand[4];
#pragma unroll
    for (int j = 0; j < 4; ++j)
        cand[j] = 4095 - (int)(__shfl(k[j], 0, 64) & 0xFFFu);

    // exact fp32 rescore of the 4 nominated candidates (unnormalized row:
    // argmax invariant under positive scaling by 1/nrm)
    float cv[4][8];
#pragma unroll
    for (int j = 0; j < 4; ++j) {
        const float* cbj = cbn + (size_t)cand[j] * DD;
        float4 c0 = *(const float4*)&cbj[lane * 8];
        float4 c1 = *(const float4*)&cbj[lane * 8 + 4];
        cv[j][0]=c0.x; cv[j][1]=c0.y; cv[j][2]=c0.z; cv[j][3]=c0.w;
        cv[j][4]=c1.x; cv[j][5]=c1.y; cv[j][6]=c1.z; cv[j][7]=c1.w;
    }
    float s[4];
#pragma unroll
    for (int j = 0; j < 4; ++j) {
        float acc = 0.f;
#pragma unroll
        for (int e = 0; e < 8; ++e) acc += orig[e] * cv[j][e];
        s[j] = acc;
    }
    waveSumN<4>(s);
    float sBest = -3e38f; int idx = 0x7fffffff, sel = 0;
#pragma unroll
    for (int j = 0; j < 4; ++j) {
        if (s[j] > sBest || (s[j] == sBest && cand[j] < idx)) {
            sBest = s[j]; idx = cand[j]; sel = j;
        }
    }

    // winning row from registers (wave-uniform sel -> cndmask tree)
    float qv[8];
#pragma unroll
    for (int e = 0; e < 8; ++e)
        qv[e] = sel == 0 ? cv[0][e] : sel == 1 ? cv[1][e]
              : sel == 2 ? cv[2][e] : cv[3][e];

    // commit loss: ||x_n - q||^2 = 2 - 2*(x_n . q) = 2 - 2*sBest/nrm
    float lrow = 2.0f - 2.0f * (sBest / nrm);

    // r = qv (rotation identity); resid -= qv; emit f16 + next rnrm
    float nres[8];
    float ss = 0.f;
#pragma unroll
    for (int j = 0; j < 8; ++j) {
        nres[j] = orig[j] - qv[j];
        ss += nres[j] * nres[j];
    }
    *(float4*)&xr[lane * 8]     = make_float4(nres[0], nres[1], nres[2], nres[3]);
    *(float4*)&xr[lane * 8 + 4] = make_float4(nres[4], nres[5], nres[6], nres[7]);
    ss = waveSum(ss);
    if (lane == 0) rnrm[row] = fmaxf(sqrtf(ss), 1e-12f);
    f16x8 hv;
#pragma unroll
    for (int j = 0; j < 8; ++j) hv[j] = (_Float16)nres[j];
    *(f16x8*)&af16[(size_t)row * DD + lane * 8] = hv;

    if (lane == 0) {
        dout[IDX_OFF + row * 4 + q] = (float)idx;
        sL[wave] = lrow;
    }
    __syncthreads();
    if (threadIdx.x == 0) {
        lossPart[(size_t)q * NBLK_FIN + blockIdx.x] =
            (sL[0] + sL[1] + sL[2] + sL[3]) * LOSS_COEF;
    }
}

// -------- qout = x - resid_final (replaces per-q dout accumulation) ----------
__global__ void qoutK(const float* __restrict__ x, const float* __restrict__ resid,
                      float* __restrict__ dout) {
    int i = blockIdx.x * blockDim.x + threadIdx.x;
    int stride = gridDim.x * blockDim.x;
    for (; i < QOUT_SZ; i += stride) dout[i] = x[i] - resid[i];
}

// -------- final loss reduce: one wave per q sums its 4096 block partials -----
__global__ void lossWriteK(const float* __restrict__ lossPart,
                           float* __restrict__ dout) {
    int q = threadIdx.x >> 6, lane = threadIdx.x & 63;
    float s = 0.f;
    for (int i = lane; i < NBLK_FIN; i += 64)
        s += lossPart[(size_t)q * NBLK_FIN + i];
    s = waveSum(s);
    if (lane == 0) dout[LOSS_OFF + q] = s;
}

extern "C" void kernel_launch(void* const* d_in, const int* in_sizes, int n_in,
                              void* d_out, int out_size, void* d_ws, size_t ws_size,
                              hipStream_t stream) {
    const float* x = (const float*)d_in[0];
    const float* codebooks = (const float*)d_in[1];
    const float* weights = (const float*)d_in[2];
    float* dout = (float*)d_out;
    float* w = (float*)d_ws;

    float* resid = w + WS_RESID;
    float* cbn   = w + WS_CBN;
    float* rnrm  = w + WS_RNRM;
    unsigned* pk = (unsigned*)(w + WS_PV);
    float* lossPart = w + WS_PI;
    _Float16* f16base = (_Float16*)(w + WS_F16);
    _Float16* Af16 = f16base + F16_A;
    _Float16* Bf16 = f16base + F16_B;
    // bf16 split buffers alias dead regions (see layout comment):
    short* cbHi = (short*)(w + WS_PV);          // 4.2 MB, aliases pk (dead here)
    short* cbLo = cbHi + (size_t)CC * DD;       // 4.2 MB, rest of pk region
    short* wHi  = (short*)(w + WS_PI + 32768);  // PI slack (lossPart uses 64 KB)
    short* wLo  = wHi + (size_t)DD * DD;

    initK<<<2048, 256, 0, stream>>>(x, resid);
    residCvtK<<<RR / 4, 256, 0, stream>>>(resid, rnrm, Af16);

    for (int q = 0; q < QQ; ++q) {
        cvtSplitK<<<512, 256, 0, stream>>>(codebooks + (size_t)q * CC * DD,
                                           cbHi, cbLo, CC * DD);
        cvtSplitK<<<128, 256, 0, stream>>>(weights + (size_t)q * DD * DD,
                                           wHi, wLo, DD * DD);
        gemmCbMfmaK<<<dim3(CC / 64, DD / 64), 256, 0, stream>>>(
            cbHi, cbLo, wHi, wLo, cbn);
        rowNormCvtK<<<CC / 4, 256, 0, stream>>>(cbn, Bf16);
        simMfmaK<<<dim3(RR / 128, CC / 128), 512, 0, stream>>>(Af16, Bf16, pk);
        finalizeK<<<RR / 4, 256, 0, stream>>>(resid, rnrm, cbn, pk,
                                              dout, lossPart, Af16, q);
    }
    qoutK<<<2048, 256, 0, stream>>>(x, resid, dout);
    lossWriteK<<<1, 256, 0, stream>>>(lossPart, dout);
}

// Round 14
// 742.140 us; speedup vs baseline: 2.4841x; 1.0139x over previous
//
#include <hip/hip_runtime.h>
#include <math.h>

// Problem constants
#define RR 16384        // B*N rows
#define DD 512          // feature dim
#define CC 4096         // codebook size
#define QQ 4            // num quantizers
#define QOUT_SZ (RR*DD)
#define IDX_OFF QOUT_SZ
#define LOSS_OFF (QOUT_SZ + RR*QQ)
#define LOSS_COEF (1.25f / 8388608.0f)
#define NBLK_FIN (RR/4)  // finalize blocks per dispatch (4096)

// Workspace layout (float offsets) -- IDENTICAL footprint to rounds 0-7
// (proven in-bounds; R8's 9 MB growth caused the container aborts).
// bf16 split buffers alias DEAD regions:
//   cbHi/cbLo (8.39 MB) -> pk region (dead between finalize(q) and simMfma(q))
//   wHi/wLo (1 MB) -> PI region slack (lossPart uses first 64 KB)
#define WS_RESID 0
#define WS_CBN   (RR*DD)                    // 8388608
#define WS_RNRM  (WS_CBN + CC*DD)           // 10485760
#define WS_PV    (WS_RNRM + RR)             // 10502144  (pk / cbHi+cbLo)
#define WS_PI    (WS_PV + RR*32*4)          // lossPart + wHi/wLo slack
#define WS_F16   (WS_PI + RR*32*4 + 4)      // 16B aligned
// f16 region (offsets in halves from WS_F16 base) -- original extent
#define F16_A 0
#define F16_B (RR*DD)

typedef _Float16 f16x8 __attribute__((ext_vector_type(8)));
typedef short bf16x8 __attribute__((ext_vector_type(8)));
typedef float f32x4 __attribute__((ext_vector_type(4)));

__device__ __forceinline__ float waveSum(float v) {
#pragma unroll
    for (int m = 1; m < 64; m <<= 1) v += __shfl_xor(v, m, 64);
    return v;
}

// interleaved N-way wave sum: N independent butterfly chains for ILP
template <int N>
__device__ __forceinline__ void waveSumN(float* v) {
#pragma unroll
    for (int m = 1; m < 64; m <<= 1) {
#pragma unroll
        for (int j = 0; j < N; ++j) v[j] += __shfl_xor(v[j], m, 64);
    }
}

// ---------- packed-key top-k machinery ----------
// key = monotone(f32 sim) truncated to top-20 bits | (4095 - col).
__device__ __forceinline__ unsigned packKey(float v, int c) {
    unsigned u = __float_as_uint(v);
    u ^= (unsigned)((int)u >> 31) | 0x80000000u;   // monotone total order
    return (u & 0xFFFFF000u) | (unsigned)(4095 - c);
}

__device__ __forceinline__ void ceDesc(unsigned &a, unsigned &b) {
    unsigned mn = a > b ? b : a;
    a = a > b ? a : b;
    b = mn;
}

// merge partner's sorted-desc 4-list into mine (bitonic top-half + sort).
__device__ __forceinline__ void merge4(unsigned k[4],
                                       unsigned b0, unsigned b1,
                                       unsigned b2, unsigned b3) {
    k[0] = k[0] > b3 ? k[0] : b3;
    k[1] = k[1] > b2 ? k[1] : b2;
    k[2] = k[2] > b1 ? k[2] : b1;
    k[3] = k[3] > b0 ? k[3] : b0;
    ceDesc(k[0], k[2]); ceDesc(k[1], k[3]);
    ceDesc(k[0], k[1]); ceDesc(k[2], k[3]);
}

__device__ __forceinline__ void merge4Shfl(unsigned k[4], int m) {
    unsigned b0 = __shfl_xor(k[0], m, 64);
    unsigned b1 = __shfl_xor(k[1], m, 64);
    unsigned b2 = __shfl_xor(k[2], m, 64);
    unsigned b3 = __shfl_xor(k[3], m, 64);
    merge4(k, b0, b1, b2, b3);
}

// RNE float -> bf16 (returned as low-16 bits)
__device__ __forceinline__ unsigned bf16rne(float x) {
    unsigned u = __float_as_uint(x);
    return (u + 0x7FFFu + ((u >> 16) & 1u)) >> 16;
}

// ---------------- init: resid = x (qout derived as x - resid_final) ---------
__global__ void initK(const float* __restrict__ x, float* __restrict__ resid) {
    int i = blockIdx.x * blockDim.x + threadIdx.x;
    int stride = gridDim.x * blockDim.x;
    for (; i < QOUT_SZ; i += stride) resid[i] = x[i];
}

// ---------------- split fp32 -> bf16 hi/lo pair ----------------
__global__ void cvtSplitK(const float* __restrict__ src, short* __restrict__ hi,
                          short* __restrict__ lo, int n) {
    int i = (blockIdx.x * blockDim.x + threadIdx.x) * 4;
    int stride = gridDim.x * blockDim.x * 4;
    for (; i < n; i += stride) {
        float4 v = *(const float4*)&src[i];
        float vv[4] = {v.x, v.y, v.z, v.w};
        short hh[4], ll[4];
#pragma unroll
        for (int j = 0; j < 4; ++j) {
            unsigned hb = bf16rne(vv[j]);
            float hf = __uint_as_float(hb << 16);
            hh[j] = (short)hb;
            ll[j] = (short)bf16rne(vv[j] - hf);
        }
        *(short4*)&hi[i] = make_short4(hh[0], hh[1], hh[2], hh[3]);
        *(short4*)&lo[i] = make_short4(ll[0], ll[1], ll[2], ll[3]);
    }
}

// ------- implicit_cb = codebooks[q] @ weights[q]^T, bf16-split MFMA ----------
// 3-product bf16 emulation C ~= AhiBhi + AhiBlo + AloBhi (rel err ~1e-5).
// Geometry: 64x64 tile, 256 thr / 4 waves (2x2), 32x32 wave tile acc[2][2],
// BK=64, verified XOR-swizzle gload_lds staging (rows == l15 mod 8).
__global__ __launch_bounds__(256)
void gemmCbMfmaK(const short* __restrict__ AHi, const short* __restrict__ ALo,
                 const short* __restrict__ BHi, const short* __restrict__ BLo,
                 float* __restrict__ out) {
    __shared__ short AH[64 * 64], AL[64 * 64];   // 16 KB
    __shared__ short BH[64 * 64], BL[64 * 64];   // 16 KB
    int t = threadIdx.x, w = t >> 6, lane = t & 63;
    int cBase = blockIdx.x * 64, dBase = blockIdx.y * 64;
    int mbase = (w & 1) * 32, nbase = (w >> 1) * 32;
    int l15 = lane & 15, quad = lane >> 4;

    f32x4 acc[2][2];
#pragma unroll
    for (int i = 0; i < 2; ++i)
#pragma unroll
        for (int j = 0; j < 2; ++j) acc[i][j] = (f32x4){0.f, 0.f, 0.f, 0.f};

    int rsub = lane >> 3;                 // 0..7 row within the 8-row group
    int swz = (lane & 7) ^ rsub;          // source 16B-chunk index

    for (int k0 = 0; k0 < DD; k0 += 64) {
        __syncthreads();
#pragma unroll
        for (int j = 0; j < 2; ++j) {
            int r0 = j * 32 + 8 * w;      // wave-uniform 8-row group base
            __builtin_amdgcn_global_load_lds(
                (const __attribute__((address_space(1))) void*)&AHi[(size_t)(cBase + r0 + rsub) * DD + k0 + swz * 8],
                (__attribute__((address_space(3))) void*)&AH[r0 * 64], 16, 0, 0);
            __builtin_amdgcn_global_load_lds(
                (const __attribute__((address_space(1))) void*)&ALo[(size_t)(cBase + r0 + rsub) * DD + k0 + swz * 8],
                (__attribute__((address_space(3))) void*)&AL[r0 * 64], 16, 0, 0);
            __builtin_amdgcn_global_load_lds(
                (const __attribute__((address_space(1))) void*)&BHi[(size_t)(dBase + r0 + rsub) * DD + k0 + swz * 8],
                (__attribute__((address_space(3))) void*)&BH[r0 * 64], 16, 0, 0);
            __builtin_amdgcn_global_load_lds(
                (const __attribute__((address_space(1))) void*)&BLo[(size_t)(dBase + r0 + rsub) * DD + k0 + swz * 8],
                (__attribute__((address_space(3))) void*)&BL[r0 * 64], 16, 0, 0);
        }
        __syncthreads();
#pragma unroll
        for (int kh = 0; kh < 2; ++kh) {
            int chunk = (kh * 4 + quad) ^ (l15 & 7);   // lds_row&7 == l15&7
            bf16x8 ah[2], al[2], bh[2], bl[2];
#pragma unroll
            for (int tm = 0; tm < 2; ++tm) {
                ah[tm] = *(const bf16x8*)&AH[(mbase + tm * 16 + l15) * 64 + chunk * 8];
                al[tm] = *(const bf16x8*)&AL[(mbase + tm * 16 + l15) * 64 + chunk * 8];
            }
#pragma unroll
            for (int tn = 0; tn < 2; ++tn) {
                bh[tn] = *(const bf16x8*)&BH[(nbase + tn * 16 + l15) * 64 + chunk * 8];
                bl[tn] = *(const bf16x8*)&BL[(nbase + tn * 16 + l15) * 64 + chunk * 8];
            }
#pragma unroll
            for (int tn = 0; tn < 2; ++tn)
#pragma unroll
                for (int tm = 0; tm < 2; ++tm) {
                    acc[tm][tn] = __builtin_amdgcn_mfma_f32_16x16x32_bf16(
                        ah[tm], bh[tn], acc[tm][tn], 0, 0, 0);
                    acc[tm][tn] = __builtin_amdgcn_mfma_f32_16x16x32_bf16(
                        ah[tm], bl[tn], acc[tm][tn], 0, 0, 0);
                    acc[tm][tn] = __builtin_amdgcn_mfma_f32_16x16x32_bf16(
                        al[tm], bh[tn], acc[tm][tn], 0, 0, 0);
                }
        }
    }

    // epilogue: D layout lane,reg r -> row = quad*4+r (in 16-tile), col = l15
#pragma unroll
    for (int tm = 0; tm < 2; ++tm)
#pragma unroll
        for (int tn = 0; tn < 2; ++tn)
#pragma unroll
            for (int r = 0; r < 4; ++r) {
                int row = cBase + mbase + tm * 16 + quad * 4 + r;
                int col = dBase + nbase + tn * 16 + l15;
                out[(size_t)row * DD + col] = acc[tm][tn][r];
            }
}

// ------- normalize cbn rows in place + emit f16 copy (one wave/row) ----------
__global__ void rowNormCvtK(float* __restrict__ buf, _Float16* __restrict__ bf16) {
    int wave = threadIdx.x >> 6, lane = threadIdx.x & 63;
    int row = blockIdx.x * 4 + wave;
    float* p = buf + (size_t)row * DD;
    float4 v0 = *(float4*)&p[lane * 8];
    float4 v1 = *(float4*)&p[lane * 8 + 4];
    float ss = v0.x*v0.x + v0.y*v0.y + v0.z*v0.z + v0.w*v0.w
             + v1.x*v1.x + v1.y*v1.y + v1.z*v1.z + v1.w*v1.w;
    ss = waveSum(ss);
    float nrm = fmaxf(sqrtf(ss), 1e-12f);
    float vals[8] = {v0.x/nrm, v0.y/nrm, v0.z/nrm, v0.w/nrm,
                     v1.x/nrm, v1.y/nrm, v1.z/nrm, v1.w/nrm};
    *(float4*)&p[lane * 8]     = make_float4(vals[0], vals[1], vals[2], vals[3]);
    *(float4*)&p[lane * 8 + 4] = make_float4(vals[4], vals[5], vals[6], vals[7]);
    f16x8 hv;
#pragma unroll
    for (int j = 0; j < 8; ++j) hv[j] = (_Float16)vals[j];
    *(f16x8*)&bf16[(size_t)row * DD + lane * 8] = hv;
}

// ------- resid row norms + f16 copy of RAW resid (q=0 only) ------------------
__global__ void residCvtK(const float* __restrict__ resid,
                          float* __restrict__ rnrm, _Float16* __restrict__ af16) {
    int wave = threadIdx.x >> 6, lane = threadIdx.x & 63;
    int row = blockIdx.x * 4 + wave;
    const float* p = resid + (size_t)row * DD;
    float4 v0 = *(const float4*)&p[lane * 8];
    float4 v1 = *(const float4*)&p[lane * 8 + 4];
    float vals[8] = {v0.x, v0.y, v0.z, v0.w, v1.x, v1.y, v1.z, v1.w};
    float ss = 0.f;
#pragma unroll
    for (int j = 0; j < 8; ++j) ss += vals[j] * vals[j];
    ss = waveSum(ss);
    if (lane == 0) rnrm[row] = fmaxf(sqrtf(ss), 1e-12f);
    f16x8 hv;
#pragma unroll
    for (int j = 0; j < 8; ++j) hv[j] = (_Float16)vals[j];
    *(f16x8*)&af16[(size_t)row * DD + lane * 8] = hv;
}

// ---------------- single-pass f16 MFMA sim GEMM + fused top-2 ----------------
// R13: m201 8-phase-style port. Six 2-barrier variants all landed at the
// documented 2-phase ceiling (608 TF == m233's 607). This is the 256x256,
// BK=64, 8-wave (2Mx4N), 4-phases-per-K-tile counted schedule: each phase
// {ds_read subtile | stage part of tile t+1 -> barrier -> setprio(1) ->
// 16 MFMA -> setprio(0) -> barrier}; tile-boundary vmcnt(0) is covered
// (loads issued 2-3 phases earlier). Staging/fragment mapping is our proven
// conflict-free XOR scheme. LDS 128 KB dbuf -> 1 block/CU (m201 precedent:
// schedule carries it). Wave tile 128x64, acc[8][4], ~200 VGPR.
__device__ __forceinline__ void simStageA(
    const _Float16* __restrict__ Af16, _Float16* dst, int rowBase, int k0s,
    int w, int rsub, int swz) {
#pragma unroll
    for (int j = 0; j < 4; ++j) {
        int r0 = j * 64 + 8 * w;
        __builtin_amdgcn_global_load_lds(
            (const __attribute__((address_space(1))) void*)&Af16[(size_t)(rowBase + r0 + rsub) * DD + k0s + swz * 8],
            (__attribute__((address_space(3))) void*)&dst[r0 * 64], 16, 0, 0);
    }
}
__device__ __forceinline__ void simStageB2(
    const _Float16* __restrict__ Bf16, _Float16* dst, int cBase, int k0s,
    int w, int rsub, int swz, int jbase) {
#pragma unroll
    for (int j = 0; j < 2; ++j) {
        int r0 = (jbase + j) * 64 + 8 * w;
        __builtin_amdgcn_global_load_lds(
            (const __attribute__((address_space(1))) void*)&Bf16[(size_t)(cBase + r0 + rsub) * DD + k0s + swz * 8],
            (__attribute__((address_space(3))) void*)&dst[r0 * 64], 16, 0, 0);
    }
}

template <int H>
__device__ __forceinline__ void readAf(const _Float16* Ab, int wr, int l15,
                                       int quad, f16x8 (&af)[4][2]) {
#pragma unroll
    for (int kh = 0; kh < 2; ++kh) {
        int chunk = (kh * 4 + quad) ^ (l15 & 7);
#pragma unroll
        for (int tm = 0; tm < 4; ++tm)
            af[tm][kh] = *(const f16x8*)&Ab[(wr * 128 + H * 64 + tm * 16 + l15) * 64 + chunk * 8];
    }
}
template <int G>
__device__ __forceinline__ void readBf(const _Float16* Bb, int wc, int l15,
                                       int quad, f16x8 (&bf)[2][2]) {
#pragma unroll
    for (int kh = 0; kh < 2; ++kh) {
        int chunk = (kh * 4 + quad) ^ (l15 & 7);
#pragma unroll
        for (int tn = 0; tn < 2; ++tn)
            bf[tn][kh] = *(const f16x8*)&Bb[(wc * 64 + G * 32 + tn * 16 + l15) * 64 + chunk * 8];
    }
}
template <int H, int G>
__device__ __forceinline__ void mfma16(const f16x8 (&af)[4][2],
                                       const f16x8 (&bf)[2][2],
                                       f32x4 (&acc)[8][4]) {
#pragma unroll
    for (int kh = 0; kh < 2; ++kh)
#pragma unroll
        for (int tn = 0; tn < 2; ++tn)
#pragma unroll
            for (int tm = 0; tm < 4; ++tm)
                acc[H * 4 + tm][G * 2 + tn] = __builtin_amdgcn_mfma_f32_16x16x32_f16(
                    af[tm][kh], bf[tn][kh], acc[H * 4 + tm][G * 2 + tn], 0, 0, 0);
}

__global__ __launch_bounds__(512, 2)
void simMfmaK(
    const _Float16* __restrict__ Af16, const _Float16* __restrict__ Bf16,
    unsigned* __restrict__ pk) {
    __shared__ _Float16 Alds[2][256 * 64];   // 64 KB
    __shared__ _Float16 Blds[2][256 * 64];   // 64 KB
    int t = threadIdx.x, w = t >> 6, lane = t & 63;
    int rowBase = blockIdx.x * 256;
    int cBase = blockIdx.y * 256;
    int wr = w >> 2, wc = w & 3;             // 2M x 4N wave grid
    int l15 = lane & 15, quad = lane >> 4;

    f32x4 acc[8][4];
#pragma unroll
    for (int i = 0; i < 8; ++i)
#pragma unroll
        for (int j = 0; j < 4; ++j) acc[i][j] = (f32x4){0.f, 0.f, 0.f, 0.f};

    int rsub = lane >> 3;                 // 0..7 row within an 8-row group
    int swz = (lane & 7) ^ rsub;          // source 16B-chunk index

    // prologue: full tile 0 into buffer 0; exposed drain once per block
    simStageA(Af16, &Alds[0][0], rowBase, 0, w, rsub, swz);
    simStageB2(Bf16, &Blds[0][0], cBase, 0, w, rsub, swz, 0);
    simStageB2(Bf16, &Blds[0][0], cBase, 0, w, rsub, swz, 2);
    asm volatile("s_waitcnt vmcnt(0)" ::: "memory");
    __builtin_amdgcn_s_barrier();
    __builtin_amdgcn_sched_barrier(0);

    f16x8 af[4][2], bf[2][2];
    for (int tt = 0; tt < 8; ++tt) {
        int b = tt & 1;
        const _Float16* Ab = b ? &Alds[1][0] : &Alds[0][0];
        const _Float16* Bb = b ? &Blds[1][0] : &Blds[0][0];
        _Float16* An = b ? &Alds[0][0] : &Alds[1][0];
        _Float16* Bn = b ? &Blds[0][0] : &Blds[1][0];
        int k0n = (tt + 1) * 64;
        bool pf = tt < 7;

        // phase 0: (H=0,G=0) + stage A(t+1)
        readAf<0>(Ab, wr, l15, quad, af);
        readBf<0>(Bb, wc, l15, quad, bf);
        if (pf) simStageA(Af16, An, rowBase, k0n, w, rsub, swz);
        __builtin_amdgcn_sched_barrier(0);
        __builtin_amdgcn_s_barrier();
        __builtin_amdgcn_s_setprio(1);
        mfma16<0, 0>(af, bf, acc);
        __builtin_amdgcn_s_setprio(0);
        __builtin_amdgcn_sched_barrier(0);
        __builtin_amdgcn_s_barrier();

        // phase 1: (H=0,G=1) + stage B(t+1) first half
        readBf<1>(Bb, wc, l15, quad, bf);
        if (pf) simStageB2(Bf16, Bn, cBase, k0n, w, rsub, swz, 0);
        __builtin_amdgcn_sched_barrier(0);
        __builtin_amdgcn_s_barrier();
        __builtin_amdgcn_s_setprio(1);
        mfma16<0, 1>(af, bf, acc);
        __builtin_amdgcn_s_setprio(0);
        __builtin_amdgcn_sched_barrier(0);
        __builtin_amdgcn_s_barrier();

        // phase 2: (H=1,G=0) + stage B(t+1) second half
        readAf<1>(Ab, wr, l15, quad, af);
        readBf<0>(Bb, wc, l15, quad, bf);
        if (pf) simStageB2(Bf16, Bn, cBase, k0n, w, rsub, swz, 2);
        __builtin_amdgcn_sched_barrier(0);
        __builtin_amdgcn_s_barrier();
        __builtin_amdgcn_s_setprio(1);
        mfma16<1, 0>(af, bf, acc);
        __builtin_amdgcn_s_setprio(0);
        __builtin_amdgcn_sched_barrier(0);
        __builtin_amdgcn_s_barrier();

        // phase 3: (H=1,G=1); no stage
        readBf<1>(Bb, wc, l15, quad, bf);
        __builtin_amdgcn_sched_barrier(0);
        __builtin_amdgcn_s_barrier();
        __builtin_amdgcn_s_setprio(1);
        mfma16<1, 1>(af, bf, acc);
        __builtin_amdgcn_s_setprio(0);

        // tile boundary: tile t+1's loads (issued phases 0-2, >=1500 cyc ago)
        if (pf) {
            __builtin_amdgcn_sched_barrier(0);
            asm volatile("s_waitcnt vmcnt(0)" ::: "memory");
            __builtin_amdgcn_s_barrier();
            __builtin_amdgcn_sched_barrier(0);
        }
    }

    // epilogue: per wave, top-2 per row over its 64 columns, packed keys.
    // D layout: lane,reg r -> row = quad*4+r (in 16-tile), col = l15
    // col of acc[tm][tn] = cBase + wc*64 + tn*16 + l15
    int gkey = (cBase >> 6) + wc;         // global 64-col group index (0..63)
#pragma unroll
    for (int tm = 0; tm < 8; ++tm) {
#pragma unroll
        for (int r = 0; r < 4; ++r) {
            unsigned t0 = packKey(acc[tm][0][r], cBase + wc * 64 + 0 * 16 + l15);
            unsigned t1 = packKey(acc[tm][1][r], cBase + wc * 64 + 1 * 16 + l15);
            unsigned t2 = packKey(acc[tm][2][r], cBase + wc * 64 + 2 * 16 + l15);
            unsigned t3 = packKey(acc[tm][3][r], cBase + wc * 64 + 3 * 16 + l15);
            // per-lane sorted top-2 of 4 keys
            ceDesc(t0, t1); ceDesc(t2, t3);
            unsigned k0 = t0 > t2 ? t0 : t2;
            unsigned mn = t0 > t2 ? t2 : t0;
            unsigned mx = t1 > t3 ? t1 : t3;
            unsigned k1 = mn > mx ? mn : mx;
            // 16-lane butterfly merge of sorted pairs
#pragma unroll
            for (int m = 1; m < 16; m <<= 1) {
                unsigned b0 = __shfl_xor(k0, m, 64);
                unsigned b1 = __shfl_xor(k1, m, 64);
                unsigned m0 = k0 > b0 ? k0 : b0;
                unsigned n0 = k0 > b0 ? b0 : k0;
                unsigned m1 = k1 > b1 ? k1 : b1;
                k0 = m0;
                k1 = n0 > m1 ? n0 : m1;
            }
            if (l15 == 0) {
                int rowg = rowBase + wr * 128 + tm * 16 + quad * 4 + r;
                *(uint2*)&pk[(size_t)rowg * 128 + gkey * 2] = make_uint2(k0, k1);
            }
        }
    }
}

// -------- finalize: merge group top-2s, fp32 rescore, resid update -----------
// Rotation-identity simplification (R12, verified): for unit-norm src/tgt,
// rotate_to's forward pass is exactly the target codebook row.
// r = cbn[idx]; resid -= cbn[idx]; lrow = 2 - 2*sim; rescore on unnormalized
// orig (argmax invariant under positive scaling).
__global__ void finalizeK(float* __restrict__ resid,
                          float* __restrict__ rnrm,
                          const float* __restrict__ cbn,
                          const unsigned* __restrict__ pk,
                          float* __restrict__ dout,
                          float* __restrict__ lossPart,
                          _Float16* __restrict__ af16, int q) {
    __shared__ float sL[4];
    int wave = threadIdx.x >> 6, lane = threadIdx.x & 63;
    int row = blockIdx.x * 4 + wave;
    float* xr = resid + (size_t)row * DD;
    float nrm = rnrm[row];
    float4 a0 = *(float4*)&xr[lane * 8];
    float4 a1 = *(float4*)&xr[lane * 8 + 4];
    float orig[8] = {a0.x,a0.y,a0.z,a0.w,a1.x,a1.y,a1.z,a1.w};

    // 128 keys per row (64 groups x sorted top-2); lane l holds group l's pair
    uint2 kp = *(const uint2*)&pk[(size_t)row * 128 + lane * 2];
    unsigned k[4] = {kp.x, kp.y, 0u, 0u};   // sorted desc (zeros lose to real keys)
#pragma unroll
    for (int m = 1; m < 64; m <<= 1) merge4Shfl(k, m);
    int cand[4];
#pragma unroll
    for (int j = 0; j < 4; ++j)
        cand[j] = 4095 - (int)(__shfl(k[j], 0, 64) & 0xFFFu);

    // exact fp32 rescore of the 4 nominated candidates (unnormalized row:
    // argmax invariant under positive scaling by 1/nrm)
    float cv[4][8];
#pragma unroll
    for (int j = 0; j < 4; ++j) {
        const float* cbj = cbn + (size_t)cand[j] * DD;
        float4 c0 = *(const float4*)&cbj[lane * 8];
        float4 c1 = *(const float4*)&cbj[lane * 8 + 4];
        cv[j][0]=c0.x; cv[j][1]=c0.y; cv[j][2]=c0.z; cv[j][3]=c0.w;
        cv[j][4]=c1.x; cv[j][5]=c1.y; cv[j][6]=c1.z; cv[j][7]=c1.w;
    }
    float s[4];
#pragma unroll
    for (int j = 0; j < 4; ++j) {
        float acc = 0.f;
#pragma unroll
        for (int e = 0; e < 8; ++e) acc += orig[e] * cv[j][e];
        s[j] = acc;
    }
    waveSumN<4>(s);
    float sBest = -3e38f; int idx = 0x7fffffff, sel = 0;
#pragma unroll
    for (int j = 0; j < 4; ++j) {
        if (s[j] > sBest || (s[j] == sBest && cand[j] < idx)) {
            sBest = s[j]; idx = cand[j]; sel = j;
        }
    }

    // winning row from registers (wave-uniform sel -> cndmask tree)
    float qv[8];
#pragma unroll
    for (int e = 0; e < 8; ++e)
        qv[e] = sel == 0 ? cv[0][e] : sel == 1 ? cv[1][e]
              : sel == 2 ? cv[2][e] : cv[3][e];

    // commit loss: ||x_n - q||^2 = 2 - 2*(x_n . q) = 2 - 2*sBest/nrm
    float lrow = 2.0f - 2.0f * (sBest / nrm);

    // r = qv (rotation identity); resid -= qv; emit f16 + next rnrm
    float nres[8];
    float ss = 0.f;
#pragma unroll
    for (int j = 0; j < 8; ++j) {
        nres[j] = orig[j] - qv[j];
        ss += nres[j] * nres[j];
    }
    *(float4*)&xr[lane * 8]     = make_float4(nres[0], nres[1], nres[2], nres[3]);
    *(float4*)&xr[lane * 8 + 4] = make_float4(nres[4], nres[5], nres[6], nres[7]);
    ss = waveSum(ss);
    if (lane == 0) rnrm[row] = fmaxf(sqrtf(ss), 1e-12f);
    f16x8 hv;
#pragma unroll
    for (int j = 0; j < 8; ++j) hv[j] = (_Float16)nres[j];
    *(f16x8*)&af16[(size_t)row * DD + lane * 8] = hv;

    if (lane == 0) {
        dout[IDX_OFF + row * 4 + q] = (float)idx;
        sL[wave] = lrow;
    }
    __syncthreads();
    if (threadIdx.x == 0) {
        lossPart[(size_t)q * NBLK_FIN + blockIdx.x] =
            (sL[0] + sL[1] + sL[2] + sL[3]) * LOSS_COEF;
    }
}

// -------- qout = x - resid_final (replaces per-q dout accumulation) ----------
__global__ void qoutK(const float* __restrict__ x, const float* __restrict__ resid,
                      float* __restrict__ dout) {
    int i = blockIdx.x * blockDim.x + threadIdx.x;
    int stride = gridDim.x * blockDim.x;
    for (; i < QOUT_SZ; i += stride) dout[i] = x[i] - resid[i];
}

// -------- final loss reduce: one wave per q sums its 4096 block partials -----
__global__ void lossWriteK(const float* __restrict__ lossPart,
                           float* __restrict__ dout) {
    int q = threadIdx.x >> 6, lane = threadIdx.x & 63;
    float s = 0.f;
    for (int i = lane; i < NBLK_FIN; i += 64)
        s += lossPart[(size_t)q * NBLK_FIN + i];
    s = waveSum(s);
    if (lane == 0) dout[LOSS_OFF + q] = s;
}

extern "C" void kernel_launch(void* const* d_in, const int* in_sizes, int n_in,
                              void* d_out, int out_size, void* d_ws, size_t ws_size,
                              hipStream_t stream) {
    const float* x = (const float*)d_in[0];
    const float* codebooks = (const float*)d_in[1];
    const float* weights = (const float*)d_in[2];
    float* dout = (float*)d_out;
    float* w = (float*)d_ws;

    float* resid = w + WS_RESID;
    float* cbn   = w + WS_CBN;
    float* rnrm  = w + WS_RNRM;
    unsigned* pk = (unsigned*)(w + WS_PV);
    float* lossPart = w + WS_PI;
    _Float16* f16base = (_Float16*)(w + WS_F16);
    _Float16* Af16 = f16base + F16_A;
    _Float16* Bf16 = f16base + F16_B;
    // bf16 split buffers alias dead regions (see layout comment):
    short* cbHi = (short*)(w + WS_PV);          // 4.2 MB, aliases pk (dead here)
    short* cbLo = cbHi + (size_t)CC * DD;       // 4.2 MB, rest of pk region
    short* wHi  = (short*)(w + WS_PI + 32768);  // PI slack (lossPart uses 64 KB)
    short* wLo  = wHi + (size_t)DD * DD;

    initK<<<2048, 256, 0, stream>>>(x, resid);
    residCvtK<<<RR / 4, 256, 0, stream>>>(resid, rnrm, Af16);

    for (int q = 0; q < QQ; ++q) {
        cvtSplitK<<<512, 256, 0, stream>>>(codebooks + (size_t)q * CC * DD,
                                           cbHi, cbLo, CC * DD);
        cvtSplitK<<<128, 256, 0, stream>>>(weights + (size_t)q * DD * DD,
                                           wHi, wLo, DD * DD);
        gemmCbMfmaK<<<dim3(CC / 64, DD / 64), 256, 0, stream>>>(
            cbHi, cbLo, wHi, wLo, cbn);
        rowNormCvtK<<<CC / 4, 256, 0, stream>>>(cbn, Bf16);
        simMfmaK<<<dim3(RR / 256, CC / 256), 512, 0, stream>>>(Af16, Bf16, pk);
        finalizeK<<<RR / 4, 256, 0, stream>>>(resid, rnrm, cbn, pk,
                                              dout, lossPart, Af16, q);
    }
    qoutK<<<2048, 256, 0, stream>>>(x, resid, dout);
    lossWriteK<<<1, 256, 0, stream>>>(lossPart, dout);
}